// Round 15
// baseline (361.569 us; speedup 1.0000x reference)
//
#include <hip/hip_runtime.h>
#include <hip/hip_bf16.h>
#include <cstddef>

using bf16 = __hip_bfloat16;
typedef __attribute__((ext_vector_type(4)))  short bf16x4;
typedef __attribute__((ext_vector_type(8)))  short bf16x8;
typedef __attribute__((ext_vector_type(4)))  float f32x4;
typedef __attribute__((ext_vector_type(16))) float f32x16;
typedef __attribute__((ext_vector_type(2)))  unsigned int uint32x2;
typedef __attribute__((ext_vector_type(4)))  unsigned int uint32x4;

#define B_   64
#define T_   512
#define V_   25
#define HD_  64
#define E_   48
#define NC_  60

__device__ __forceinline__ bf16  f2b(float x){ return __float2bfloat16(x); }
__device__ __forceinline__ unsigned short f2bits(float x){ return __builtin_bit_cast(unsigned short, f2b(x)); }
__device__ __forceinline__ float bits2f(unsigned short s){ return __builtin_bit_cast(float, ((unsigned)s)<<16); }
__device__ __forceinline__ float rbf(float x){ return bits2f(f2bits(x)); }
__device__ __forceinline__ unsigned cvtpk(float lo, float hi){
  unsigned r;
  asm("v_cvt_pk_bf16_f32 %0, %1, %2" : "=v"(r) : "v"(lo), "v"(hi));
  return r;
}
__device__ __forceinline__ short cvt1(float x){ return (short)(unsigned short)cvtpk(x, x); }

// ---------------- prep: weight packing + CSR ----------------
__global__ void k_wt(const float* __restrict__ c1W, const float* __restrict__ c2W,
                     const float* __restrict__ s2W, const float* __restrict__ W2,
                     const float* __restrict__ s1W, const float* __restrict__ W1,
                     const int* __restrict__ ei,
                     bf16* __restrict__ Wb, bf16* __restrict__ Wb2,
                     bf16* __restrict__ WbB, bf16* __restrict__ W6f,
                     int* __restrict__ offs, int* __restrict__ lst)
{
  int i0 = blockIdx.x*blockDim.x + threadIdx.x, stride = gridDim.x*blockDim.x;
  if(blockIdx.x == 0 && threadIdx.x == 0){
    int cnt[V_], pos[V_];
    for(int v=0;v<V_;v++) cnt[v]=0;
    for(int e=0;e<E_;e++) cnt[ei[2*e+1]]++;
    int off = 0;
    for(int v=0;v<V_;v++){ offs[v]=off; pos[v]=off; off+=cnt[v]; }
    offs[V_] = off;
    for(int e=0;e<E_;e++){ int d = ei[2*e+1]; lst[pos[d]++] = ei[2*e+0]; }
  }
  for(int i = i0; i < 307200; i += stride){
    int hlo = i & 15, o = (i>>4)&63, kc = (i>>10)%12, v = i/12288;
    int ks = kc>>2, h = (kc&3)*16 + hlo;
    Wb[i] = f2b(c1W[(o*1600 + v*64 + h)*3 + ks]);
  }
  for(int i = i0; i < 24576; i += stride){
    int hlo = i & 15, o = (i>>4)&127, kc = i>>11;
    int ks = kc>>2, c = (kc&3)*16 + hlo;
    Wb2[i] = f2b(c2W[(o*64 + c)*3 + ks]);
  }
  for(int i = i0; i < 8192; i += stride){
    int j = i&7, l=(i>>3)&63, n=(i>>9)&3, kt=i>>11;
    int k = kt*32 + (l>>4)*8 + j;
    int h = n*16 + (l&15);
    float val = (k < 64) ? s2W[k*64 + h] : W2[(k-64)*64 + h];
    WbB[i] = f2b(val);
  }
  for(int i = i0; i < 2048; i += stride){
    int j = i&7, l=(i>>3)&63, n=(i>>9)&3;
    int k = (l>>4)*8 + j, h = n*16 + (l&15);
    float val = 0.f;
    if(k < 3) val = s1W[k*64 + h];
    else if(k < 6) val = W1[(k-3)*64 + h];
    W6f[i] = f2b(val);
  }
}

// ---------------- BN1 stats via 6x6 Gram partials ----------------
__global__ __launch_bounds__(512) void k_stats1(
    const float* __restrict__ X,
    const int* __restrict__ offs, const int* __restrict__ lst,
    float* __restrict__ gpart)
{
  int tid = threadIdx.x;
  int b = blockIdx.y, t0 = blockIdx.x*16;
  __shared__ short Xs[1248];
  __shared__ short Z6[3200];
  __shared__ unsigned char soc[32], slc[48];

  if(tid < V_+1) soc[tid] = (unsigned char)offs[tid];
  else if(tid >= 64 && tid < 64+E_) slc[tid-64] = (unsigned char)lst[tid-64];
  for(int i=tid; i<1248; i+=512){
    int c = i/416, r = i - c*416, tl = r/26, v = r - tl*26;
    short val = 0;
    if(v < 25) val = cvt1(X[((size_t)(b*3+c)*T_ + t0+tl)*V_ + v]);
    Xs[i] = val;
  }
  __syncthreads();
  if(tid < 400){
    int v = tid>>4, tl = tid&15, xb = tl*26;
    float a0=0.f, a1=0.f, a2=0.f;
    int e1 = soc[v+1];
    for(int e=soc[v]; e<e1; e++){
      int u = slc[e];
      a0 += bits2f((unsigned short)Xs[xb+u]);
      a1 += bits2f((unsigned short)Xs[416+xb+u]);
      a2 += bits2f((unsigned short)Xs[832+xb+u]);
    }
    unsigned p01 = cvtpk(a0, a1);
    bf16x8 z;
    z[0]=Xs[xb+v]; z[1]=Xs[416+xb+v]; z[2]=Xs[832+xb+v];
    z[3]=(short)p01; z[4]=(short)(p01>>16); z[5]=cvt1(a2);
    z[6]=0; z[7]=0;
    *(bf16x8*)&Z6[tid*8] = z;
  }
  __syncthreads();

  int t = tid>>5, item = tid&31;
  if(item < 27){
    int k = item, kk = -1;
    if(item >= 6){
      int r = item - 6; k = 0;
      while(r >= 6-k){ r -= 6-k; k++; }
      kk = k + r;
    }
    float acc = 0.f;
    for(int v=0;v<25;v++){
      const short* z = &Z6[(v*16 + t)*8];
      float a = bits2f((unsigned short)z[k]);
      if(kk < 0) acc += a;
      else acc += a * bits2f((unsigned short)z[kk]);
    }
    gpart[((size_t)blockIdx.x*64 + b)*432 + t*27 + item] = acc;
  }
}

// ---------------- BN1 finalize from Gram partials ----------------
__global__ __launch_bounds__(256) void k_bnfin1(
    const float* __restrict__ gpart,
    const float* __restrict__ s1W, const float* __restrict__ W1,
    const float* __restrict__ g, const float* __restrict__ bt,
    float* __restrict__ scale, float* __restrict__ shift)
{
  int tid = threadIdx.x;
  int t0 = blockIdx.x*4;
  int tx = t0 >> 4, tlb = t0 & 15;
  __shared__ float SM[4][27];
  __shared__ float Wsh[6][64];
  for(int i=tid; i<108; i+=256){
    int tl = i/27, item = i%27;
    float s = 0.f;
    for(int b=0;b<64;b++)
      s += gpart[((size_t)tx*64 + b)*432 + (tlb+tl)*27 + item];
    SM[tl][item] = s;
  }
  for(int i=tid; i<384; i+=256){
    int k = i>>6, h = i&63;
    float w = (k<3) ? s1W[k*64+h] : W1[(k-3)*64+h];
    Wsh[k][h] = rbf(w);
  }
  __syncthreads();
  int tl = tid>>6, h = tid&63;
  float w[6];
  #pragma unroll
  for(int k=0;k<6;k++) w[k] = Wsh[k][h];
  float lin = 0.f;
  #pragma unroll
  for(int k=0;k<6;k++) lin += w[k]*SM[tl][k];
  float qq = 0.f;
  int idx = 6;
  #pragma unroll
  for(int k=0;k<6;k++){
    #pragma unroll 6
    for(int kk=k;kk<6;kk++){
      float c = w[k]*w[kk];
      if(kk != k) c += c;
      qq += c*SM[tl][idx++];
    }
  }
  float m = lin * (1.0f/1600.0f);
  float v = qq * (1.0f/1600.0f) - m*m;
  float r = rsqrtf(fmaxf(v, 0.f) + 1e-5f);
  float sc = g[h]*r;
  scale[(t0+tl)*64 + h] = sc;
  shift[(t0+tl)*64 + h] = bt[h] - m*sc;
}

// ---------------- per-(t,h) BN finalize from block partials (BN2) ----------------
__global__ void k_bnfin_th(const float* __restrict__ part,
                           const float* __restrict__ g, const float* __restrict__ bt,
                           float* __restrict__ scale, float* __restrict__ shift)
{
  int i = blockIdx.x*blockDim.x + threadIdx.x;
  if(i < T_*HD_){
    int h = i & 63, t = i >> 6, bx = t >> 4, tl = t & 15;
    const float* p = part + ((size_t)bx*64)*2048 + tl*64 + h;
    float s = 0.f, q = 0.f;
    for(int b=0;b<64;b++){ s += p[(size_t)b*2048]; q += p[(size_t)b*2048 + 1024]; }
    float m = s * (1.0f/1600.0f);
    float v = q * (1.0f/1600.0f) - m*m;
    float r = rsqrtf(fmaxf(v, 0.f) + 1e-5f);
    float sc = g[h]*r;
    scale[i] = sc;
    shift[i] = bt[h] - m*sc;
  }
}

// ---------------- GCN layer 2: MFMA recompute of H1 + MFMA layer-2, write H2 (fp8) ----------------
__global__ __launch_bounds__(512,4) void k_gcn2(
    const float* __restrict__ X,
    const float* __restrict__ scale1, const float* __restrict__ shift1,
    const bf16* __restrict__ W6f, const bf16* __restrict__ WbB,
    const int* __restrict__ offs, const int* __restrict__ lst,
    unsigned char* __restrict__ Hout, float* __restrict__ part)
{
  int tid = threadIdx.x, lane = tid & 63, wid = tid >> 6;
  int b = blockIdx.y, t0 = blockIdx.x*16;
  __shared__ short Zs[400*72];
  __shared__ short WbBs[8192];
  __shared__ unsigned int pss[1024];
  __shared__ unsigned char soc[32], slc[48];
  short* Z6 = Zs;
  short* Xs = Zs + 3200;

  bf16x8 w6[4];
  #pragma unroll
  for(int n=0;n<4;n++) w6[n] = *(const bf16x8*)&W6f[(n*64 + lane)*8];

  if(tid < V_+1) soc[tid] = (unsigned char)offs[tid];
  else if(tid >= 64 && tid < 64+E_) slc[tid-64] = (unsigned char)lst[tid-64];
  for(int i=tid; i<1024; i+=512){
    pss[i] = ((unsigned)f2bits(shift1[t0*64+i])<<16) | f2bits(scale1[t0*64+i]);
    *(bf16x8*)&WbBs[i*8] = *(const bf16x8*)&WbB[i*8];
  }
  for(int i=tid; i<1248; i+=512){
    int c = i/416, r = i - c*416, tl = r/26, v = r - tl*26;
    short val = 0;
    if(v < 25) val = cvt1(X[((size_t)(b*3+c)*T_ + t0+tl)*V_ + v]);
    Xs[i] = val;
  }
  __syncthreads();

  if(tid < 400){
    int v = tid>>4, tl = tid&15, xb = tl*26;
    float a0=0.f, a1=0.f, a2=0.f;
    int e1 = soc[v+1];
    for(int e=soc[v]; e<e1; e++){
      int u = slc[e];
      a0 += bits2f((unsigned short)Xs[xb+u]);
      a1 += bits2f((unsigned short)Xs[416+xb+u]);
      a2 += bits2f((unsigned short)Xs[832+xb+u]);
    }
    unsigned p01 = cvtpk(a0, a1);
    bf16x8 z;
    z[0]=Xs[xb+v]; z[1]=Xs[416+xb+v]; z[2]=Xs[832+xb+v];
    z[3]=(short)p01; z[4]=(short)(p01>>16); z[5]=cvt1(a2);
    z[6]=0; z[7]=0;
    *(bf16x8*)&Z6[tid*8] = z;
  }
  __syncthreads();

  // pass 1: H1pre = Z6 @ W6
  f32x4 c1f[4][4] = {};
  #pragma unroll
  for(int vi=0; vi<4; vi++){
    int v = wid + vi*8;
    if(v < V_){
      bf16x8 af = {0,0,0,0,0,0,0,0};
      if(lane < 16) af = *(const bf16x8*)&Z6[(v*16 + lane)*8];
      #pragma unroll
      for(int n=0;n<4;n++)
        c1f[vi][n] = __builtin_amdgcn_mfma_f32_16x16x32_bf16(af, w6[n], c1f[vi][n], 0, 0, 0);
    }
  }
  __syncthreads();

  // epilogue 1: bn1 + relu + pack into Zs
  int l15 = lane & 15, tlb = (lane>>4)*4;
  #pragma unroll
  for(int vi=0; vi<4; vi++){
    int v = wid + vi*8;
    if(v < V_){
      #pragma unroll
      for(int n=0;n<4;n++){
        float y[4];
        #pragma unroll
        for(int j=0;j<4;j++){
          unsigned u = pss[(tlb+j)*64 + n*16 + l15];
          y[j] = fmaxf(c1f[vi][n][j]*bits2f((unsigned short)(u&0xffffu)) + bits2f((unsigned short)(u>>16)), 0.f);
        }
        unsigned p01 = cvtpk(y[0], y[1]), p23 = cvtpk(y[2], y[3]);
        short* base = &Zs[(v*16 + tlb)*72 + n*16 + l15];
        base[0]   = (short)p01;  base[72]  = (short)(p01>>16);
        base[144] = (short)p23;  base[216] = (short)(p23>>16);
      }
    }
  }
  __syncthreads();

  // pass 2: layer-2 MFMA with in-register neighbor aggregation
  int cg = (lane>>4)*8;
  f32x4 accs[4][4] = {};
  #pragma unroll
  for(int vi=0; vi<4; vi++){
    int v = wid + vi*8;
    if(v < V_){
      const short* rowp = &Zs[(v*16 + l15)*72 + cg];
      bf16x8 a0 = *(const bf16x8*)rowp;
      bf16x8 a1 = *(const bf16x8*)(rowp + 32);
      float s0[8]={0,0,0,0,0,0,0,0}, s1[8]={0,0,0,0,0,0,0,0};
      int e1 = soc[v+1];
      for(int e=soc[v]; e<e1; e++){
        int u = slc[e];
        const short* np = &Zs[(u*16 + l15)*72 + cg];
        bf16x8 n0 = *(const bf16x8*)np;
        bf16x8 n1 = *(const bf16x8*)(np + 32);
        #pragma unroll
        for(int j=0;j<8;j++){ s0[j] += bits2f((unsigned short)n0[j]); s1[j] += bits2f((unsigned short)n1[j]); }
      }
      uint32x4 ua2, ua3;
      #pragma unroll
      for(int j=0;j<4;j++){ ua2[j] = cvtpk(s0[2*j], s0[2*j+1]); ua3[j] = cvtpk(s1[2*j], s1[2*j+1]); }
      bf16x8 a2 = __builtin_bit_cast(bf16x8, ua2);
      bf16x8 a3 = __builtin_bit_cast(bf16x8, ua3);
      #pragma unroll
      for(int n=0;n<4;n++){
        bf16x8 b0 = *(const bf16x8*)&WbBs[(( 0+n)*64 + lane)*8];
        accs[vi][n] = __builtin_amdgcn_mfma_f32_16x16x32_bf16(a0, b0, accs[vi][n], 0, 0, 0);
        bf16x8 b1 = *(const bf16x8*)&WbBs[(( 4+n)*64 + lane)*8];
        accs[vi][n] = __builtin_amdgcn_mfma_f32_16x16x32_bf16(a1, b1, accs[vi][n], 0, 0, 0);
        bf16x8 b2 = *(const bf16x8*)&WbBs[(( 8+n)*64 + lane)*8];
        accs[vi][n] = __builtin_amdgcn_mfma_f32_16x16x32_bf16(a2, b2, accs[vi][n], 0, 0, 0);
        bf16x8 b3 = *(const bf16x8*)&WbBs[((12+n)*64 + lane)*8];
        accs[vi][n] = __builtin_amdgcn_mfma_f32_16x16x32_bf16(a3, b3, accs[vi][n], 0, 0, 0);
      }
    }
  }
  __syncthreads();

  // epilogue 2: stats + bf16 transpose via Zs
  f32x4 ssum[4] = {}, ssq[4] = {};
  #pragma unroll
  for(int vi=0; vi<4; vi++){
    int v = wid + vi*8;
    if(v < V_){
      #pragma unroll
      for(int n=0;n<4;n++){
        float val[4];
        #pragma unroll
        for(int j=0;j<4;j++){
          val[j] = accs[vi][n][j];
          ssum[n][j] += val[j]; ssq[n][j] += val[j]*val[j];
        }
        unsigned p01 = cvtpk(val[0], val[1]), p23 = cvtpk(val[2], val[3]);
        short* base = &Zs[(tlb*25 + v)*72 + n*16 + l15];
        base[0]    = (short)p01;  base[1800] = (short)(p01>>16);
        base[3600] = (short)p23;  base[5400] = (short)(p23>>16);
      }
    }
  }
  __syncthreads();

  unsigned char* hbout = Hout + ((size_t)b*T_ + t0)*V_*64;
  for(int c=tid; c<3200; c+=512){
    bf16x8 o = *(const bf16x8*)&Zs[(c>>3)*72 + (c&7)*8];
    float f[8];
    #pragma unroll
    for(int j=0;j<8;j++) f[j] = bits2f((unsigned short)o[j]);
    int w0 = 0, w1 = 0;
    w0 = __builtin_amdgcn_cvt_pk_fp8_f32(f[0], f[1], w0, false);
    w0 = __builtin_amdgcn_cvt_pk_fp8_f32(f[2], f[3], w0, true);
    w1 = __builtin_amdgcn_cvt_pk_fp8_f32(f[4], f[5], w1, false);
    w1 = __builtin_amdgcn_cvt_pk_fp8_f32(f[6], f[7], w1, true);
    uint32x2 st; st.x = (unsigned)w0; st.y = (unsigned)w1;
    __builtin_nontemporal_store(st, (uint32x2*)&hbout[(size_t)c*8]);
  }
  __syncthreads();

  // stats: single pass via LDS float atomics
  float* red = (float*)Zs;
  for(int i=tid; i<2048; i+=512) red[i] = 0.f;
  __syncthreads();
  #pragma unroll
  for(int n=0;n<4;n++)
    #pragma unroll
    for(int j=0;j<4;j++){
      atomicAdd(&red[(tlb+j)*64 + n*16 + l15], ssum[n][j]);
      atomicAdd(&red[1024 + (tlb+j)*64 + n*16 + l15], ssq[n][j]);
    }
  __syncthreads();
  size_t pb = ((size_t)blockIdx.x*64 + blockIdx.y)*2048;
  for(int i=tid; i<2048; i+=512)
    __builtin_nontemporal_store(red[i], &part[pb + i]);
}

// ---------------- conv1: 32-t tiles, in-block v-split, depth-2 prefetch ----------------
__device__ __forceinline__ uint32x2 loadH8(const unsigned char* H, int b, int v, int t0, int s){
  int ti = s>>3, h0 = (s&7)*8, t = t0-1+ti;
  uint32x2 r; r.x = 0u; r.y = 0u;
  if(t >= 0 && t < T_) r = *(const uint32x2*)&H[(((size_t)b*T_+t)*V_ + v)*HD_ + h0];
  return r;
}

__device__ __forceinline__ void xform_store(short* zbuf, const unsigned int* sshf, int s, uint32x2 raw){
  int ti = s>>3, h0 = (s&7)*8;
  uint4 u0 = *(const uint4*)&sshf[ti*64 + h0];
  uint4 u1 = *(const uint4*)&sshf[ti*64 + h0 + 4];
  unsigned int uu[8] = {u0.x,u0.y,u0.z,u0.w,u1.x,u1.y,u1.z,u1.w};
  float x[8];
  x[0] = __builtin_amdgcn_cvt_f32_fp8((int)raw.x, 0);
  x[1] = __builtin_amdgcn_cvt_f32_fp8((int)raw.x, 1);
  x[2] = __builtin_amdgcn_cvt_f32_fp8((int)raw.x, 2);
  x[3] = __builtin_amdgcn_cvt_f32_fp8((int)raw.x, 3);
  x[4] = __builtin_amdgcn_cvt_f32_fp8((int)raw.y, 0);
  x[5] = __builtin_amdgcn_cvt_f32_fp8((int)raw.y, 1);
  x[6] = __builtin_amdgcn_cvt_f32_fp8((int)raw.y, 2);
  x[7] = __builtin_amdgcn_cvt_f32_fp8((int)raw.y, 3);
  float r[8];
  #pragma unroll
  for(int j=0;j<8;j++){
    float scl = bits2f((unsigned short)(uu[j] & 0xffffu));
    float shf = bits2f((unsigned short)(uu[j] >> 16));
    r[j] = fmaxf(x[j]*scl + shf, 0.f);
  }
  uint32x4 u;
  #pragma unroll
  for(int j=0;j<4;j++) u[j] = cvtpk(r[2*j], r[2*j+1]);
  *(uint32x4*)&zbuf[ti*72 + h0] = u;
}

__global__ __launch_bounds__(256) void k_conv1(
    const unsigned char* __restrict__ H, const float* __restrict__ scale2, const float* __restrict__ shift2,
    const bf16* __restrict__ Wb, bf16* __restrict__ C1b, float* __restrict__ cpart1)
{
  int b = blockIdx.y, t0 = blockIdx.x*32, tid = threadIdx.x;
  int lane = tid & 63, w = tid >> 6;
  __shared__ unsigned int sshf[34*64];
  __shared__ short zs[2][2][34*72];

  for(int i = tid; i < 34*64; i += 256){
    int ti = i>>6, h = i&63, t = t0-1+ti;
    unsigned int u = 0;
    if(t >= 0 && t < T_){
      u = ((unsigned)f2bits(shift2[t*64+h])<<16) | f2bits(scale2[t*64+h]);
    }
    sshf[i] = u;
  }
  __syncthreads();

  {
    uint32x2 a0 = loadH8(H,b,0,t0,tid);
    uint32x2 b0 = loadH8(H,b,13,t0,tid);
    uint32x2 a1, b1; a1.x=a1.y=b1.x=b1.y=0u;
    if(tid<16){ a1 = loadH8(H,b,0,t0,tid+256); b1 = loadH8(H,b,13,t0,tid+256); }
    xform_store(&zs[0][0][0], sshf, tid, a0);
    xform_store(&zs[1][0][0], sshf, tid, b0);
    if(tid<16){ xform_store(&zs[0][0][0], sshf, tid+256, a1); xform_store(&zs[1][0][0], sshf, tid+256, b1); }
  }
  uint32x2 rA0 = loadH8(H,b,1,t0,tid), rB0 = loadH8(H,b,14,t0,tid);
  uint32x2 rA1, rB1; rA1.x=rA1.y=rB1.x=rB1.y=0u;
  if(tid<16){ rA1 = loadH8(H,b,1,t0,tid+256); rB1 = loadH8(H,b,14,t0,tid+256); }
  __syncthreads();

  int g = w >> 1;
  int o0 = (w & 1)*32;
  int vbase = g ? 13 : 0, nv = g ? 12 : 13;
  f32x16 acc = {};
  for(int i=0; i<13; i++){
    uint32x2 nA0, nA1, nB0, nB1;
    nA0.x=nA0.y=nA1.x=nA1.y=nB0.x=nB0.y=nB1.x=nB1.y=0u;
    if(i+2 < 13){
      nA0 = loadH8(H,b,i+2,t0,tid);
      if(tid<16) nA1 = loadH8(H,b,i+2,t0,tid+256);
    }
    if(i+2 < 12){
      nB0 = loadH8(H,b,13+i+2,t0,tid);
      if(tid<16) nB1 = loadH8(H,b,13+i+2,t0,tid+256);
    }
    if(i < nv){
      int v = vbase + i;
      const short* zbuf = &zs[g][i&1][0];
      #pragma unroll
      for(int kc=0; kc<12; kc++){
        int ks = kc>>2;
        bf16x8 af = *(const bf16x8*)&Wb[((v*12+kc)*64 + o0 + (lane&31))*16 + (lane>>5)*8];
        int row = (lane&31) + ks;
        int col = (kc&3)*16 + (lane>>5)*8;
        bf16x8 bfr = *(const bf16x8*)&zbuf[row*72 + col];
        acc = __builtin_amdgcn_mfma_f32_32x32x16_bf16(af, bfr, acc, 0, 0, 0);
      }
    }
    if(i+1 < 13){
      xform_store(&zs[0][(i+1)&1][0], sshf, tid, rA0);
      if(tid<16) xform_store(&zs[0][(i+1)&1][0], sshf, tid+256, rA1);
    }
    if(i+1 < 12){
      xform_store(&zs[1][(i+1)&1][0], sshf, tid, rB0);
      if(tid<16) xform_store(&zs[1][(i+1)&1][0], sshf, tid+256, rB1);
    }
    rA0=nA0; rA1=nA1; rB0=nB0; rB1=nB1;
    __syncthreads();
  }

  float* redB = (float*)&zs[0][0][0];
  short* Cs   = &zs[0][0][0] + 4224;
  if(g == 1){
    #pragma unroll
    for(int r=0;r<16;r++){
      int ol = (r&3) + 8*(r>>2) + 4*(lane>>5);
      redB[(w&1)*1056 + ol*33 + (lane&31)] = acc[r];
    }
  }
  __syncthreads();
  if(g == 0){
    #pragma unroll
    for(int r=0;r<16;r++){
      int ol = (r&3) + 8*(r>>2) + 4*(lane>>5);
      float val = acc[r] + redB[(w&1)*1056 + ol*33 + (lane&31)];
      Cs[((w&1)*32 + ol)*32 + (lane&31)] = cvt1(val);
    }
  }
  __syncthreads();

  {
    int o = tid>>2, tseg = (tid&3)*8;
    bf16x8 row = *(const bf16x8*)&Cs[o*32 + tseg];
    *(bf16x8*)&C1b[((size_t)b*64 + o)*T_ + t0 + tseg] = row;
  }
  if(tid < 64){
    float s = 0.f, q = 0.f;
    for(int t=0;t<32;t++){
      float v = bits2f((unsigned short)Cs[tid*32 + t]);
      s += v; q += v*v;
    }
    size_t pb = ((size_t)blockIdx.y*16 + blockIdx.x)*128;
    cpart1[pb + tid] = s;
    cpart1[pb + 64 + tid] = q;
  }
}

// ---------------- parallel per-channel BN finalize ----------------
__global__ __launch_bounds__(256) void k_redch(const float* __restrict__ cpart,
    const float* __restrict__ g, const float* __restrict__ bt,
    float* __restrict__ scale, float* __restrict__ shift, int nch, int nblk, float inv_count)
{
  int o = blockIdx.x, tid = threadIdx.x;
  float s = 0.f, q = 0.f;
  for(int blk=tid; blk<nblk; blk+=256){
    s += cpart[(size_t)blk*2*nch + o];
    q += cpart[(size_t)blk*2*nch + nch + o];
  }
  for(int off=32; off; off>>=1){ s += __shfl_down(s, off); q += __shfl_down(q, off); }
  __shared__ float rs[4], rq[4];
  if((tid&63)==0){ rs[tid>>6]=s; rq[tid>>6]=q; }
  __syncthreads();
  if(tid==0){
    s = rs[0]+rs[1]+rs[2]+rs[3]; q = rq[0]+rq[1]+rq[2]+rq[3];
    float m = s*inv_count;
    float v = q*inv_count - m*m;
    float r = rsqrtf(fmaxf(v, 0.f) + 1e-5f);
    float sc = g[o]*r;
    scale[o] = sc; shift[o] = bt[o] - m*sc;
  }
}

// ---------------- conv2 via MFMA + fused BN4 partials (C2 bf16) ----------------
__global__ __launch_bounds__(256) void k_conv2(
    const bf16* __restrict__ C1b, const float* __restrict__ scale3, const float* __restrict__ shift3,
    const bf16* __restrict__ Wb2, short* __restrict__ C2b, float* __restrict__ cpart)
{
  int b = blockIdx.y, t0 = blockIdx.x*64, tid = threadIdx.x;
  int lane = tid & 63, w = tid >> 6;
  __shared__ short zT[68*72];
  __shared__ float scl[64], shf[64];
  __shared__ float rpart[4][16][2][2];
  if(tid < 64){ scl[tid]=scale3[tid]; shf[tid]=shift3[tid]; }
  __syncthreads();
  for(int i=tid; i<4352; i+=256){
    int c = i/68, r = i%68, t = t0 - 2 + r;
    float val = 0.f;
    if(t >= 0 && t < T_) val = fmaxf(bits2f((unsigned short)__builtin_bit_cast(short, C1b[((size_t)b*64+c)*T_ + t]))*scl[c] + shf[c], 0.f);
    zT[r*72 + c] = cvt1(val);
  }
  __syncthreads();
  int o0 = w*32;
  float sr[16], qr[16];
  #pragma unroll
  for(int r=0;r<16;r++){ sr[r]=0.f; qr[r]=0.f; }
  #pragma unroll
  for(int tt=0; tt<2; tt++){
    int twv = tt*32;
    f32x16 acc = {};
    #pragma unroll
    for(int kc=0; kc<12; kc++){
      bf16x8 af = *(const bf16x8*)&Wb2[((kc*128) + o0 + (lane&31))*16 + (lane>>5)*8];
      bf16x8 bfr = *(const bf16x8*)&zT[(twv + (lane&31) + 2*(kc>>2))*72 + (kc&3)*16 + (lane>>5)*8];
      acc = __builtin_amdgcn_mfma_f32_32x32x16_bf16(af, bfr, acc, 0, 0, 0);
    }
    int t = t0 + twv + (lane&31);
    #pragma unroll
    for(int r=0;r<16;r++){
      int o = o0 + (r&3) + 8*(r>>2) + 4*(lane>>5);
      float y = acc[r];
      C2b[((size_t)b*128 + o)*T_ + t] = cvt1(y);
      sr[r] += y; qr[r] += y*y;
    }
  }
  #pragma unroll
  for(int r=0;r<16;r++){
    float s = sr[r], q = qr[r];
    #pragma unroll
    for(int m=1;m<=16;m<<=1){ s += __shfl_xor(s, m); q += __shfl_xor(q, m); }
    if((lane&31)==0){ rpart[w][r][lane>>5][0]=s; rpart[w][r][lane>>5][1]=q; }
  }
  __syncthreads();
  if(tid < 128){
    int wv = tid>>5, r = (tid>>1)&15, hf = tid&1;
    int o = wv*32 + (r&3) + 8*(r>>2) + 4*hf;
    size_t pb = ((size_t)(blockIdx.y*8 + blockIdx.x))*256;
    cpart[pb + o]       = rpart[wv][r][hf][0];
    cpart[pb + 128 + o] = rpart[wv][r][hf][1];
  }
}

// ---------------- head part 1: BN+ReLU + partial t-sums ----------------
__global__ __launch_bounds__(256) void k_head1(
    const short* __restrict__ C2b, const float* __restrict__ scale4, const float* __restrict__ shift4,
    float* __restrict__ hpart)
{
  int b = blockIdx.y, q = blockIdx.x, tid = threadIdx.x;
  __shared__ float ms[256];
  int ch = tid >> 1, p = tid & 1;
  float scl = scale4[ch], shf = shift4[ch];
  const short* src = C2b + ((size_t)b*128 + ch)*T_ + q*128 + p*64;
  float s = 0.f;
  for(int i=0;i<8;i++){
    bf16x8 v8 = *(const bf16x8*)&src[i*8];
    #pragma unroll
    for(int j=0;j<8;j++) s += fmaxf(bits2f((unsigned short)v8[j])*scl + shf, 0.f);
  }
  ms[tid] = s;
  __syncthreads();
  if(tid < 128) hpart[((size_t)b*4 + q)*128 + tid] = ms[2*tid] + ms[2*tid+1];
}

// ---------------- head part 2: mean + FC ----------------
__global__ __launch_bounds__(128) void k_head2(
    const float* __restrict__ hpart, const float* __restrict__ fcW, const float* __restrict__ fcb,
    float* __restrict__ out)
{
  int b = blockIdx.x, tid = threadIdx.x;
  __shared__ float mean[128];
  const float* hp = hpart + (size_t)b*512;
  mean[tid] = (hp[tid] + hp[128+tid] + hp[256+tid] + hp[384+tid]) * (1.0f/512.0f);
  __syncthreads();
  if(tid < NC_){
    float acc = fcb[tid];
    for(int c=0;c<128;c++) acc += mean[c]*fcW[c*NC_ + tid];
    out[b*NC_ + tid] = acc;
  }
}

// ---------------- launch ----------------
extern "C" void kernel_launch(void* const* d_in, const int* in_sizes, int n_in,
                              void* d_out, int out_size, void* d_ws, size_t ws_size,
                              hipStream_t stream)
{
  const float* X   = (const float*)d_in[0];
  const int*   ei  = (const int*)  d_in[1];
  const float* W1  = (const float*)d_in[2];
  const float* s1W = (const float*)d_in[3];
  const float* g1  = (const float*)d_in[5];
  const float* b1  = (const float*)d_in[6];
  const float* W2  = (const float*)d_in[7];
  const float* s2W = (const float*)d_in[8];
  const float* g2  = (const float*)d_in[10];
  const float* b2  = (const float*)d_in[11];
  const float* c1W = (const float*)d_in[12];
  const float* tg1 = (const float*)d_in[14];
  const float* tb1 = (const float*)d_in[15];
  const float* c2W = (const float*)d_in[16];
  const float* tg2 = (const float*)d_in[18];
  const float* tb2 = (const float*)d_in[19];
  const float* fcW = (const float*)d_in[20];
  const float* fcb = (const float*)d_in[21];

  char* ws = (char*)d_ws;
  unsigned char* H = (unsigned char*)(ws);           // H2 fp8, 52 MB
  bf16*  C1b    = (bf16*) (ws + 104857600);
  float* cpart1 = (float*)(ws + 109051904);          // 512 KB; later hpart (128 KB)
  float* cpart2 = (float*)(ws + 109576192);
  float* part   = (float*)(ws + 113246208);          // 16.7 MB: gram/BN2 partials; later C2 bf16
  float* gpart  = part;
  short* C2b    = (short*)part;
  float* hpart  = cpart1;
  bf16*  Wb     = (bf16*) (ws + 130023424);
  bf16*  Wb2    = (bf16*) (ws + 131252224);
  bf16*  WbB    = (bf16*) (ws + 131350528);
  float* stats  = (float*)(ws + 131366912);
  bf16*  W6f    = (bf16*) (stats);
  float* scale1 = stats + 131456; float* shift1 = scale1 + 32768;
  float* scale2 = shift1 + 32768; float* shift2 = scale2 + 32768;
  float* scale3 = shift2 + 32768; float* shift3 = scale3 + 64;
  float* scale4 = shift3 + 64;    float* shift4 = scale4 + 128;
  int* csr_off = (int*)(shift4 + 128);
  int* csr_lst = csr_off + 32;

  k_wt<<<256, 256, 0, stream>>>(c1W, c2W, s2W, W2, s1W, W1, ei, Wb, Wb2, WbB, W6f, csr_off, csr_lst);

  k_stats1<<<dim3(T_/16, B_), 512, 0, stream>>>(X, csr_off, csr_lst, gpart);
  k_bnfin1<<<128, 256, 0, stream>>>(gpart, s1W, W1, g1, b1, scale1, shift1);
  k_gcn2<<<dim3(T_/16, B_), 512, 0, stream>>>(X, scale1, shift1, W6f, WbB, csr_off, csr_lst, H, part);
  k_bnfin_th<<<128, 256, 0, stream>>>(part, g2, b2, scale2, shift2);
  k_conv1<<<dim3(16, B_), 256, 0, stream>>>(H, scale2, shift2, Wb, C1b, cpart1);
  k_redch<<<64, 256, 0, stream>>>(cpart1, tg1, tb1, scale3, shift3, 64, 1024, 1.0f/32768.0f);
  k_conv2<<<dim3(8, B_), 256, 0, stream>>>(C1b, scale3, shift3, Wb2, C2b, cpart2);
  k_redch<<<128, 256, 0, stream>>>(cpart2, tg2, tb2, scale4, shift4, 128, 512, 1.0f/32768.0f);
  k_head1<<<dim3(4, B_), 256, 0, stream>>>(C2b, scale4, shift4, hpart);
  k_head2<<<B_, 128, 0, stream>>>(hpart, fcW, fcb, (float*)d_out);
}

// Round 16
// 201.488 us; speedup vs baseline: 1.7945x; 1.7945x over previous
//
#include <hip/hip_runtime.h>
#include <hip/hip_bf16.h>
#include <cstddef>

using bf16 = __hip_bfloat16;
typedef __attribute__((ext_vector_type(4)))  short bf16x4;
typedef __attribute__((ext_vector_type(8)))  short bf16x8;
typedef __attribute__((ext_vector_type(4)))  float f32x4;
typedef __attribute__((ext_vector_type(16))) float f32x16;
typedef __attribute__((ext_vector_type(2)))  unsigned int uint32x2;
typedef __attribute__((ext_vector_type(4)))  unsigned int uint32x4;

#define B_   64
#define T_   512
#define V_   25
#define HD_  64
#define E_   48
#define NC_  60

__device__ __forceinline__ bf16  f2b(float x){ return __float2bfloat16(x); }
__device__ __forceinline__ unsigned short f2bits(float x){ return __builtin_bit_cast(unsigned short, f2b(x)); }
__device__ __forceinline__ float bits2f(unsigned short s){ return __builtin_bit_cast(float, ((unsigned)s)<<16); }
__device__ __forceinline__ float rbf(float x){ return bits2f(f2bits(x)); }
__device__ __forceinline__ unsigned cvtpk(float lo, float hi){
  unsigned r;
  asm("v_cvt_pk_bf16_f32 %0, %1, %2" : "=v"(r) : "v"(lo), "v"(hi));
  return r;
}
__device__ __forceinline__ short cvt1(float x){ return (short)(unsigned short)cvtpk(x, x); }

// ---------------- prep: weight packing + CSR ----------------
__global__ void k_wt(const float* __restrict__ c1W, const float* __restrict__ c2W,
                     const float* __restrict__ s2W, const float* __restrict__ W2,
                     const float* __restrict__ s1W, const float* __restrict__ W1,
                     const int* __restrict__ ei,
                     bf16* __restrict__ Wb, bf16* __restrict__ Wb2,
                     bf16* __restrict__ WbB, bf16* __restrict__ W6f,
                     int* __restrict__ offs, int* __restrict__ lst)
{
  int i0 = blockIdx.x*blockDim.x + threadIdx.x, stride = gridDim.x*blockDim.x;
  if(blockIdx.x == 0 && threadIdx.x == 0){
    int cnt[V_], pos[V_];
    for(int v=0;v<V_;v++) cnt[v]=0;
    for(int e=0;e<E_;e++) cnt[ei[2*e+1]]++;
    int off = 0;
    for(int v=0;v<V_;v++){ offs[v]=off; pos[v]=off; off+=cnt[v]; }
    offs[V_] = off;
    for(int e=0;e<E_;e++){ int d = ei[2*e+1]; lst[pos[d]++] = ei[2*e+0]; }
  }
  for(int i = i0; i < 307200; i += stride){
    int hlo = i & 15, o = (i>>4)&63, kc = (i>>10)%12, v = i/12288;
    int ks = kc>>2, h = (kc&3)*16 + hlo;
    Wb[i] = f2b(c1W[(o*1600 + v*64 + h)*3 + ks]);
  }
  for(int i = i0; i < 24576; i += stride){
    int hlo = i & 15, o = (i>>4)&127, kc = i>>11;
    int ks = kc>>2, c = (kc&3)*16 + hlo;
    Wb2[i] = f2b(c2W[(o*64 + c)*3 + ks]);
  }
  for(int i = i0; i < 8192; i += stride){
    int j = i&7, l=(i>>3)&63, n=(i>>9)&3, kt=i>>11;
    int k = kt*32 + (l>>4)*8 + j;
    int h = n*16 + (l&15);
    float val = (k < 64) ? s2W[k*64 + h] : W2[(k-64)*64 + h];
    WbB[i] = f2b(val);
  }
  for(int i = i0; i < 2048; i += stride){
    int j = i&7, l=(i>>3)&63, n=(i>>9)&3;
    int k = (l>>4)*8 + j, h = n*16 + (l&15);
    float val = 0.f;
    if(k < 3) val = s1W[k*64 + h];
    else if(k < 6) val = W1[(k-3)*64 + h];
    W6f[i] = f2b(val);
  }
}

// ---------------- BN1 stats via 6x6 Gram partials ----------------
__global__ __launch_bounds__(512) void k_stats1(
    const float* __restrict__ X,
    const int* __restrict__ offs, const int* __restrict__ lst,
    float* __restrict__ gpart)
{
  int tid = threadIdx.x;
  int b = blockIdx.y, t0 = blockIdx.x*16;
  __shared__ short Xs[1248];
  __shared__ short Z6[3200];
  __shared__ unsigned char soc[32], slc[48];

  if(tid < V_+1) soc[tid] = (unsigned char)offs[tid];
  else if(tid >= 64 && tid < 64+E_) slc[tid-64] = (unsigned char)lst[tid-64];
  for(int i=tid; i<1248; i+=512){
    int c = i/416, r = i - c*416, tl = r/26, v = r - tl*26;
    short val = 0;
    if(v < 25) val = cvt1(X[((size_t)(b*3+c)*T_ + t0+tl)*V_ + v]);
    Xs[i] = val;
  }
  __syncthreads();
  if(tid < 400){
    int v = tid>>4, tl = tid&15, xb = tl*26;
    float a0=0.f, a1=0.f, a2=0.f;
    int e1 = soc[v+1];
    for(int e=soc[v]; e<e1; e++){
      int u = slc[e];
      a0 += bits2f((unsigned short)Xs[xb+u]);
      a1 += bits2f((unsigned short)Xs[416+xb+u]);
      a2 += bits2f((unsigned short)Xs[832+xb+u]);
    }
    unsigned p01 = cvtpk(a0, a1);
    bf16x8 z;
    z[0]=Xs[xb+v]; z[1]=Xs[416+xb+v]; z[2]=Xs[832+xb+v];
    z[3]=(short)p01; z[4]=(short)(p01>>16); z[5]=cvt1(a2);
    z[6]=0; z[7]=0;
    *(bf16x8*)&Z6[tid*8] = z;
  }
  __syncthreads();

  int t = tid>>5, item = tid&31;
  if(item < 27){
    int k = item, kk = -1;
    if(item >= 6){
      int r = item - 6; k = 0;
      while(r >= 6-k){ r -= 6-k; k++; }
      kk = k + r;
    }
    float acc = 0.f;
    for(int v=0;v<25;v++){
      const short* z = &Z6[(v*16 + t)*8];
      float a = bits2f((unsigned short)z[k]);
      if(kk < 0) acc += a;
      else acc += a * bits2f((unsigned short)z[kk]);
    }
    gpart[((size_t)blockIdx.x*64 + b)*432 + t*27 + item] = acc;
  }
}

// ---------------- BN1 finalize from Gram partials ----------------
__global__ __launch_bounds__(256) void k_bnfin1(
    const float* __restrict__ gpart,
    const float* __restrict__ s1W, const float* __restrict__ W1,
    const float* __restrict__ g, const float* __restrict__ bt,
    float* __restrict__ scale, float* __restrict__ shift)
{
  int tid = threadIdx.x;
  int t0 = blockIdx.x*4;
  int tx = t0 >> 4, tlb = t0 & 15;
  __shared__ float SM[4][27];
  __shared__ float Wsh[6][64];
  for(int i=tid; i<108; i+=256){
    int tl = i/27, item = i%27;
    float s = 0.f;
    for(int b=0;b<64;b++)
      s += gpart[((size_t)tx*64 + b)*432 + (tlb+tl)*27 + item];
    SM[tl][item] = s;
  }
  for(int i=tid; i<384; i+=256){
    int k = i>>6, h = i&63;
    float w = (k<3) ? s1W[k*64+h] : W1[(k-3)*64+h];
    Wsh[k][h] = rbf(w);
  }
  __syncthreads();
  int tl = tid>>6, h = tid&63;
  float w[6];
  #pragma unroll
  for(int k=0;k<6;k++) w[k] = Wsh[k][h];
  float lin = 0.f;
  #pragma unroll
  for(int k=0;k<6;k++) lin += w[k]*SM[tl][k];
  float qq = 0.f;
  int idx = 6;
  #pragma unroll
  for(int k=0;k<6;k++){
    #pragma unroll 6
    for(int kk=k;kk<6;kk++){
      float c = w[k]*w[kk];
      if(kk != k) c += c;
      qq += c*SM[tl][idx++];
    }
  }
  float m = lin * (1.0f/1600.0f);
  float v = qq * (1.0f/1600.0f) - m*m;
  float r = rsqrtf(fmaxf(v, 0.f) + 1e-5f);
  float sc = g[h]*r;
  scale[(t0+tl)*64 + h] = sc;
  shift[(t0+tl)*64 + h] = bt[h] - m*sc;
}

// ---------------- per-(t,h) BN finalize from block partials (BN2) ----------------
__global__ void k_bnfin_th(const float* __restrict__ part,
                           const float* __restrict__ g, const float* __restrict__ bt,
                           float* __restrict__ scale, float* __restrict__ shift)
{
  int i = blockIdx.x*blockDim.x + threadIdx.x;
  if(i < T_*HD_){
    int h = i & 63, t = i >> 6, bx = t >> 4, tl = t & 15;
    const float* p = part + ((size_t)bx*64)*2048 + tl*64 + h;
    float s = 0.f, q = 0.f;
    for(int b=0;b<64;b++){ s += p[(size_t)b*2048]; q += p[(size_t)b*2048 + 1024]; }
    float m = s * (1.0f/1600.0f);
    float v = q * (1.0f/1600.0f) - m*m;
    float r = rsqrtf(fmaxf(v, 0.f) + 1e-5f);
    float sc = g[h]*r;
    scale[i] = sc;
    shift[i] = bt[h] - m*sc;
  }
}

// ---------------- GCN layer 2: MFMA recompute of H1 + MFMA layer-2, write H2 (fp8) ----------------
__global__ __launch_bounds__(512,4) void k_gcn2(
    const float* __restrict__ X,
    const float* __restrict__ scale1, const float* __restrict__ shift1,
    const bf16* __restrict__ W6f, const bf16* __restrict__ WbB,
    const int* __restrict__ offs, const int* __restrict__ lst,
    unsigned char* __restrict__ Hout, float* __restrict__ part)
{
  int tid = threadIdx.x, lane = tid & 63, wid = tid >> 6;
  int b = blockIdx.y, t0 = blockIdx.x*16;
  __shared__ short Zs[400*72];
  __shared__ short WbBs[8192];
  __shared__ unsigned int pss[1024];
  __shared__ unsigned char soc[32], slc[48];
  short* Z6 = Zs;
  short* Xs = Zs + 3200;

  bf16x8 w6[4];
  #pragma unroll
  for(int n=0;n<4;n++) w6[n] = *(const bf16x8*)&W6f[(n*64 + lane)*8];

  if(tid < V_+1) soc[tid] = (unsigned char)offs[tid];
  else if(tid >= 64 && tid < 64+E_) slc[tid-64] = (unsigned char)lst[tid-64];
  for(int i=tid; i<1024; i+=512){
    pss[i] = ((unsigned)f2bits(shift1[t0*64+i])<<16) | f2bits(scale1[t0*64+i]);
    *(bf16x8*)&WbBs[i*8] = *(const bf16x8*)&WbB[i*8];
  }
  for(int i=tid; i<1248; i+=512){
    int c = i/416, r = i - c*416, tl = r/26, v = r - tl*26;
    short val = 0;
    if(v < 25) val = cvt1(X[((size_t)(b*3+c)*T_ + t0+tl)*V_ + v]);
    Xs[i] = val;
  }
  __syncthreads();

  if(tid < 400){
    int v = tid>>4, tl = tid&15, xb = tl*26;
    float a0=0.f, a1=0.f, a2=0.f;
    int e1 = soc[v+1];
    for(int e=soc[v]; e<e1; e++){
      int u = slc[e];
      a0 += bits2f((unsigned short)Xs[xb+u]);
      a1 += bits2f((unsigned short)Xs[416+xb+u]);
      a2 += bits2f((unsigned short)Xs[832+xb+u]);
    }
    unsigned p01 = cvtpk(a0, a1);
    bf16x8 z;
    z[0]=Xs[xb+v]; z[1]=Xs[416+xb+v]; z[2]=Xs[832+xb+v];
    z[3]=(short)p01; z[4]=(short)(p01>>16); z[5]=cvt1(a2);
    z[6]=0; z[7]=0;
    *(bf16x8*)&Z6[tid*8] = z;
  }
  __syncthreads();

  // pass 1: H1pre = Z6 @ W6
  f32x4 c1f[4][4] = {};
  #pragma unroll
  for(int vi=0; vi<4; vi++){
    int v = wid + vi*8;
    if(v < V_){
      bf16x8 af = {0,0,0,0,0,0,0,0};
      if(lane < 16) af = *(const bf16x8*)&Z6[(v*16 + lane)*8];
      #pragma unroll
      for(int n=0;n<4;n++)
        c1f[vi][n] = __builtin_amdgcn_mfma_f32_16x16x32_bf16(af, w6[n], c1f[vi][n], 0, 0, 0);
    }
  }
  __syncthreads();

  // epilogue 1: bn1 + relu + pack into Zs
  int l15 = lane & 15, tlb = (lane>>4)*4;
  #pragma unroll
  for(int vi=0; vi<4; vi++){
    int v = wid + vi*8;
    if(v < V_){
      #pragma unroll
      for(int n=0;n<4;n++){
        float y[4];
        #pragma unroll
        for(int j=0;j<4;j++){
          unsigned u = pss[(tlb+j)*64 + n*16 + l15];
          y[j] = fmaxf(c1f[vi][n][j]*bits2f((unsigned short)(u&0xffffu)) + bits2f((unsigned short)(u>>16)), 0.f);
        }
        unsigned p01 = cvtpk(y[0], y[1]), p23 = cvtpk(y[2], y[3]);
        short* base = &Zs[(v*16 + tlb)*72 + n*16 + l15];
        base[0]   = (short)p01;  base[72]  = (short)(p01>>16);
        base[144] = (short)p23;  base[216] = (short)(p23>>16);
      }
    }
  }
  __syncthreads();

  // pass 2: layer-2 MFMA with in-register neighbor aggregation
  int cg = (lane>>4)*8;
  f32x4 accs[4][4] = {};
  #pragma unroll
  for(int vi=0; vi<4; vi++){
    int v = wid + vi*8;
    if(v < V_){
      const short* rowp = &Zs[(v*16 + l15)*72 + cg];
      bf16x8 a0 = *(const bf16x8*)rowp;
      bf16x8 a1 = *(const bf16x8*)(rowp + 32);
      float s0[8]={0,0,0,0,0,0,0,0}, s1[8]={0,0,0,0,0,0,0,0};
      int e1 = soc[v+1];
      for(int e=soc[v]; e<e1; e++){
        int u = slc[e];
        const short* np = &Zs[(u*16 + l15)*72 + cg];
        bf16x8 n0 = *(const bf16x8*)np;
        bf16x8 n1 = *(const bf16x8*)(np + 32);
        #pragma unroll
        for(int j=0;j<8;j++){ s0[j] += bits2f((unsigned short)n0[j]); s1[j] += bits2f((unsigned short)n1[j]); }
      }
      uint32x4 ua2, ua3;
      #pragma unroll
      for(int j=0;j<4;j++){ ua2[j] = cvtpk(s0[2*j], s0[2*j+1]); ua3[j] = cvtpk(s1[2*j], s1[2*j+1]); }
      bf16x8 a2 = __builtin_bit_cast(bf16x8, ua2);
      bf16x8 a3 = __builtin_bit_cast(bf16x8, ua3);
      #pragma unroll
      for(int n=0;n<4;n++){
        bf16x8 b0 = *(const bf16x8*)&WbBs[(( 0+n)*64 + lane)*8];
        accs[vi][n] = __builtin_amdgcn_mfma_f32_16x16x32_bf16(a0, b0, accs[vi][n], 0, 0, 0);
        bf16x8 b1 = *(const bf16x8*)&WbBs[(( 4+n)*64 + lane)*8];
        accs[vi][n] = __builtin_amdgcn_mfma_f32_16x16x32_bf16(a1, b1, accs[vi][n], 0, 0, 0);
        bf16x8 b2 = *(const bf16x8*)&WbBs[(( 8+n)*64 + lane)*8];
        accs[vi][n] = __builtin_amdgcn_mfma_f32_16x16x32_bf16(a2, b2, accs[vi][n], 0, 0, 0);
        bf16x8 b3 = *(const bf16x8*)&WbBs[((12+n)*64 + lane)*8];
        accs[vi][n] = __builtin_amdgcn_mfma_f32_16x16x32_bf16(a3, b3, accs[vi][n], 0, 0, 0);
      }
    }
  }
  __syncthreads();

  // epilogue 2: stats + bf16 transpose via Zs
  f32x4 ssum[4] = {}, ssq[4] = {};
  #pragma unroll
  for(int vi=0; vi<4; vi++){
    int v = wid + vi*8;
    if(v < V_){
      #pragma unroll
      for(int n=0;n<4;n++){
        float val[4];
        #pragma unroll
        for(int j=0;j<4;j++){
          val[j] = accs[vi][n][j];
          ssum[n][j] += val[j]; ssq[n][j] += val[j]*val[j];
        }
        unsigned p01 = cvtpk(val[0], val[1]), p23 = cvtpk(val[2], val[3]);
        short* base = &Zs[(tlb*25 + v)*72 + n*16 + l15];
        base[0]    = (short)p01;  base[1800] = (short)(p01>>16);
        base[3600] = (short)p23;  base[5400] = (short)(p23>>16);
      }
    }
  }
  __syncthreads();

  unsigned char* hbout = Hout + ((size_t)b*T_ + t0)*V_*64;
  for(int c=tid; c<3200; c+=512){
    bf16x8 o = *(const bf16x8*)&Zs[(c>>3)*72 + (c&7)*8];
    float f[8];
    #pragma unroll
    for(int j=0;j<8;j++) f[j] = bits2f((unsigned short)o[j]);
    int w0 = 0, w1 = 0;
    w0 = __builtin_amdgcn_cvt_pk_fp8_f32(f[0], f[1], w0, false);
    w0 = __builtin_amdgcn_cvt_pk_fp8_f32(f[2], f[3], w0, true);
    w1 = __builtin_amdgcn_cvt_pk_fp8_f32(f[4], f[5], w1, false);
    w1 = __builtin_amdgcn_cvt_pk_fp8_f32(f[6], f[7], w1, true);
    uint32x2 st; st.x = (unsigned)w0; st.y = (unsigned)w1;
    __builtin_nontemporal_store(st, (uint32x2*)&hbout[(size_t)c*8]);
  }
  __syncthreads();

  // stats: two conflict-free passes through red = Zs
  float* red = (float*)Zs;
  size_t pb = ((size_t)blockIdx.x*64 + blockIdx.y)*2048;
  #pragma unroll
  for(int n=0;n<4;n++)
    #pragma unroll
    for(int j=0;j<4;j++)
      red[wid*1024 + (tlb+j)*64 + n*16 + l15] = ssum[n][j];
  __syncthreads();
  for(int i=tid; i<1024; i+=512){
    float s = 0.f;
    #pragma unroll
    for(int w=0;w<8;w++) s += red[w*1024 + i];
    __builtin_nontemporal_store(s, &part[pb + i]);
  }
  __syncthreads();
  #pragma unroll
  for(int n=0;n<4;n++)
    #pragma unroll
    for(int j=0;j<4;j++)
      red[wid*1024 + (tlb+j)*64 + n*16 + l15] = ssq[n][j];
  __syncthreads();
  for(int i=tid; i<1024; i+=512){
    float q = 0.f;
    #pragma unroll
    for(int w=0;w<8;w++) q += red[w*1024 + i];
    __builtin_nontemporal_store(q, &part[pb + 1024 + i]);
  }
}

// ---------------- conv1: 32-t tiles, in-block v-split, depth-2 prefetch ----------------
__device__ __forceinline__ uint32x2 loadH8(const unsigned char* H, int b, int v, int t0, int s){
  int ti = s>>3, h0 = (s&7)*8, t = t0-1+ti;
  uint32x2 r; r.x = 0u; r.y = 0u;
  if(t >= 0 && t < T_) r = *(const uint32x2*)&H[(((size_t)b*T_+t)*V_ + v)*HD_ + h0];
  return r;
}

__device__ __forceinline__ void xform_store(short* zbuf, const unsigned int* sshf, int s, uint32x2 raw){
  int ti = s>>3, h0 = (s&7)*8;
  uint4 u0 = *(const uint4*)&sshf[ti*64 + h0];
  uint4 u1 = *(const uint4*)&sshf[ti*64 + h0 + 4];
  unsigned int uu[8] = {u0.x,u0.y,u0.z,u0.w,u1.x,u1.y,u1.z,u1.w};
  float x[8];
  x[0] = __builtin_amdgcn_cvt_f32_fp8((int)raw.x, 0);
  x[1] = __builtin_amdgcn_cvt_f32_fp8((int)raw.x, 1);
  x[2] = __builtin_amdgcn_cvt_f32_fp8((int)raw.x, 2);
  x[3] = __builtin_amdgcn_cvt_f32_fp8((int)raw.x, 3);
  x[4] = __builtin_amdgcn_cvt_f32_fp8((int)raw.y, 0);
  x[5] = __builtin_amdgcn_cvt_f32_fp8((int)raw.y, 1);
  x[6] = __builtin_amdgcn_cvt_f32_fp8((int)raw.y, 2);
  x[7] = __builtin_amdgcn_cvt_f32_fp8((int)raw.y, 3);
  float r[8];
  #pragma unroll
  for(int j=0;j<8;j++){
    float scl = bits2f((unsigned short)(uu[j] & 0xffffu));
    float shf = bits2f((unsigned short)(uu[j] >> 16));
    r[j] = fmaxf(x[j]*scl + shf, 0.f);
  }
  uint32x4 u;
  #pragma unroll
  for(int j=0;j<4;j++) u[j] = cvtpk(r[2*j], r[2*j+1]);
  *(uint32x4*)&zbuf[ti*72 + h0] = u;
}

__global__ __launch_bounds__(256) void k_conv1(
    const unsigned char* __restrict__ H, const float* __restrict__ scale2, const float* __restrict__ shift2,
    const bf16* __restrict__ Wb, bf16* __restrict__ C1b, float* __restrict__ cpart1)
{
  int b = blockIdx.y, t0 = blockIdx.x*32, tid = threadIdx.x;
  int lane = tid & 63, w = tid >> 6;
  __shared__ unsigned int sshf[34*64];
  __shared__ short zs[2][2][34*72];

  for(int i = tid; i < 34*64; i += 256){
    int ti = i>>6, h = i&63, t = t0-1+ti;
    unsigned int u = 0;
    if(t >= 0 && t < T_){
      u = ((unsigned)f2bits(shift2[t*64+h])<<16) | f2bits(scale2[t*64+h]);
    }
    sshf[i] = u;
  }
  __syncthreads();

  {
    uint32x2 a0 = loadH8(H,b,0,t0,tid);
    uint32x2 b0 = loadH8(H,b,13,t0,tid);
    uint32x2 a1, b1; a1.x=a1.y=b1.x=b1.y=0u;
    if(tid<16){ a1 = loadH8(H,b,0,t0,tid+256); b1 = loadH8(H,b,13,t0,tid+256); }
    xform_store(&zs[0][0][0], sshf, tid, a0);
    xform_store(&zs[1][0][0], sshf, tid, b0);
    if(tid<16){ xform_store(&zs[0][0][0], sshf, tid+256, a1); xform_store(&zs[1][0][0], sshf, tid+256, b1); }
  }
  uint32x2 rA0 = loadH8(H,b,1,t0,tid), rB0 = loadH8(H,b,14,t0,tid);
  uint32x2 rA1, rB1; rA1.x=rA1.y=rB1.x=rB1.y=0u;
  if(tid<16){ rA1 = loadH8(H,b,1,t0,tid+256); rB1 = loadH8(H,b,14,t0,tid+256); }
  __syncthreads();

  int g = w >> 1;
  int o0 = (w & 1)*32;
  int vbase = g ? 13 : 0, nv = g ? 12 : 13;
  f32x16 acc = {};
  for(int i=0; i<13; i++){
    uint32x2 nA0, nA1, nB0, nB1;
    nA0.x=nA0.y=nA1.x=nA1.y=nB0.x=nB0.y=nB1.x=nB1.y=0u;
    if(i+2 < 13){
      nA0 = loadH8(H,b,i+2,t0,tid);
      if(tid<16) nA1 = loadH8(H,b,i+2,t0,tid+256);
    }
    if(i+2 < 12){
      nB0 = loadH8(H,b,13+i+2,t0,tid);
      if(tid<16) nB1 = loadH8(H,b,13+i+2,t0,tid+256);
    }
    if(i < nv){
      int v = vbase + i;
      const short* zbuf = &zs[g][i&1][0];
      #pragma unroll
      for(int kc=0; kc<12; kc++){
        int ks = kc>>2;
        bf16x8 af = *(const bf16x8*)&Wb[((v*12+kc)*64 + o0 + (lane&31))*16 + (lane>>5)*8];
        int row = (lane&31) + ks;
        int col = (kc&3)*16 + (lane>>5)*8;
        bf16x8 bfr = *(const bf16x8*)&zbuf[row*72 + col];
        acc = __builtin_amdgcn_mfma_f32_32x32x16_bf16(af, bfr, acc, 0, 0, 0);
      }
    }
    if(i+1 < 13){
      xform_store(&zs[0][(i+1)&1][0], sshf, tid, rA0);
      if(tid<16) xform_store(&zs[0][(i+1)&1][0], sshf, tid+256, rA1);
    }
    if(i+1 < 12){
      xform_store(&zs[1][(i+1)&1][0], sshf, tid, rB0);
      if(tid<16) xform_store(&zs[1][(i+1)&1][0], sshf, tid+256, rB1);
    }
    rA0=nA0; rA1=nA1; rB0=nB0; rB1=nB1;
    __syncthreads();
  }

  float* redB = (float*)&zs[0][0][0];
  short* Cs   = &zs[0][0][0] + 4224;
  if(g == 1){
    #pragma unroll
    for(int r=0;r<16;r++){
      int ol = (r&3) + 8*(r>>2) + 4*(lane>>5);
      redB[(w&1)*1056 + ol*33 + (lane&31)] = acc[r];
    }
  }
  __syncthreads();
  if(g == 0){
    #pragma unroll
    for(int r=0;r<16;r++){
      int ol = (r&3) + 8*(r>>2) + 4*(lane>>5);
      float val = acc[r] + redB[(w&1)*1056 + ol*33 + (lane&31)];
      Cs[((w&1)*32 + ol)*32 + (lane&31)] = cvt1(val);
    }
  }
  __syncthreads();

  {
    int o = tid>>2, tseg = (tid&3)*8;
    bf16x8 row = *(const bf16x8*)&Cs[o*32 + tseg];
    *(bf16x8*)&C1b[((size_t)b*64 + o)*T_ + t0 + tseg] = row;
  }
  if(tid < 64){
    float s = 0.f, q = 0.f;
    for(int t=0;t<32;t++){
      float v = bits2f((unsigned short)Cs[tid*32 + t]);
      s += v; q += v*v;
    }
    size_t pb = ((size_t)blockIdx.y*16 + blockIdx.x)*128;
    cpart1[pb + tid] = s;
    cpart1[pb + 64 + tid] = q;
  }
}

// ---------------- parallel per-channel BN finalize ----------------
__global__ __launch_bounds__(256) void k_redch(const float* __restrict__ cpart,
    const float* __restrict__ g, const float* __restrict__ bt,
    float* __restrict__ scale, float* __restrict__ shift, int nch, int nblk, float inv_count)
{
  int o = blockIdx.x, tid = threadIdx.x;
  float s = 0.f, q = 0.f;
  for(int blk=tid; blk<nblk; blk+=256){
    s += cpart[(size_t)blk*2*nch + o];
    q += cpart[(size_t)blk*2*nch + nch + o];
  }
  for(int off=32; off; off>>=1){ s += __shfl_down(s, off); q += __shfl_down(q, off); }
  __shared__ float rs[4], rq[4];
  if((tid&63)==0){ rs[tid>>6]=s; rq[tid>>6]=q; }
  __syncthreads();
  if(tid==0){
    s = rs[0]+rs[1]+rs[2]+rs[3]; q = rq[0]+rq[1]+rq[2]+rq[3];
    float m = s*inv_count;
    float v = q*inv_count - m*m;
    float r = rsqrtf(fmaxf(v, 0.f) + 1e-5f);
    float sc = g[o]*r;
    scale[o] = sc; shift[o] = bt[o] - m*sc;
  }
}

// ---------------- conv2 via MFMA + fused BN4 partials (C2 bf16) ----------------
__global__ __launch_bounds__(256) void k_conv2(
    const bf16* __restrict__ C1b, const float* __restrict__ scale3, const float* __restrict__ shift3,
    const bf16* __restrict__ Wb2, short* __restrict__ C2b, float* __restrict__ cpart)
{
  int b = blockIdx.y, t0 = blockIdx.x*64, tid = threadIdx.x;
  int lane = tid & 63, w = tid >> 6;
  __shared__ short zT[68*72];
  __shared__ float scl[64], shf[64];
  __shared__ float rpart[4][16][2][2];
  if(tid < 64){ scl[tid]=scale3[tid]; shf[tid]=shift3[tid]; }
  __syncthreads();
  for(int i=tid; i<4352; i+=256){
    int c = i/68, r = i%68, t = t0 - 2 + r;
    float val = 0.f;
    if(t >= 0 && t < T_) val = fmaxf(bits2f((unsigned short)__builtin_bit_cast(short, C1b[((size_t)b*64+c)*T_ + t]))*scl[c] + shf[c], 0.f);
    zT[r*72 + c] = cvt1(val);
  }
  __syncthreads();
  int o0 = w*32;
  float sr[16], qr[16];
  #pragma unroll
  for(int r=0;r<16;r++){ sr[r]=0.f; qr[r]=0.f; }
  #pragma unroll
  for(int tt=0; tt<2; tt++){
    int twv = tt*32;
    f32x16 acc = {};
    #pragma unroll
    for(int kc=0; kc<12; kc++){
      bf16x8 af = *(const bf16x8*)&Wb2[((kc*128) + o0 + (lane&31))*16 + (lane>>5)*8];
      bf16x8 bfr = *(const bf16x8*)&zT[(twv + (lane&31) + 2*(kc>>2))*72 + (kc&3)*16 + (lane>>5)*8];
      acc = __builtin_amdgcn_mfma_f32_32x32x16_bf16(af, bfr, acc, 0, 0, 0);
    }
    int t = t0 + twv + (lane&31);
    #pragma unroll
    for(int r=0;r<16;r++){
      int o = o0 + (r&3) + 8*(r>>2) + 4*(lane>>5);
      float y = acc[r];
      C2b[((size_t)b*128 + o)*T_ + t] = cvt1(y);
      sr[r] += y; qr[r] += y*y;
    }
  }
  #pragma unroll
  for(int r=0;r<16;r++){
    float s = sr[r], q = qr[r];
    #pragma unroll
    for(int m=1;m<=16;m<<=1){ s += __shfl_xor(s, m); q += __shfl_xor(q, m); }
    if((lane&31)==0){ rpart[w][r][lane>>5][0]=s; rpart[w][r][lane>>5][1]=q; }
  }
  __syncthreads();
  if(tid < 128){
    int wv = tid>>5, r = (tid>>1)&15, hf = tid&1;
    int o = wv*32 + (r&3) + 8*(r>>2) + 4*hf;
    size_t pb = ((size_t)(blockIdx.y*8 + blockIdx.x))*256;
    cpart[pb + o]       = rpart[wv][r][hf][0];
    cpart[pb + 128 + o] = rpart[wv][r][hf][1];
  }
}

// ---------------- head part 1: BN+ReLU + partial t-sums ----------------
__global__ __launch_bounds__(256) void k_head1(
    const short* __restrict__ C2b, const float* __restrict__ scale4, const float* __restrict__ shift4,
    float* __restrict__ hpart)
{
  int b = blockIdx.y, q = blockIdx.x, tid = threadIdx.x;
  __shared__ float ms[256];
  int ch = tid >> 1, p = tid & 1;
  float scl = scale4[ch], shf = shift4[ch];
  const short* src = C2b + ((size_t)b*128 + ch)*T_ + q*128 + p*64;
  float s = 0.f;
  for(int i=0;i<8;i++){
    bf16x8 v8 = *(const bf16x8*)&src[i*8];
    #pragma unroll
    for(int j=0;j<8;j++) s += fmaxf(bits2f((unsigned short)v8[j])*scl + shf, 0.f);
  }
  ms[tid] = s;
  __syncthreads();
  if(tid < 128) hpart[((size_t)b*4 + q)*128 + tid] = ms[2*tid] + ms[2*tid+1];
}

// ---------------- head part 2: mean + FC ----------------
__global__ __launch_bounds__(128) void k_head2(
    const float* __restrict__ hpart, const float* __restrict__ fcW, const float* __restrict__ fcb,
    float* __restrict__ out)
{
  int b = blockIdx.x, tid = threadIdx.x;
  __shared__ float mean[128];
  const float* hp = hpart + (size_t)b*512;
  mean[tid] = (hp[tid] + hp[128+tid] + hp[256+tid] + hp[384+tid]) * (1.0f/512.0f);
  __syncthreads();
  if(tid < NC_){
    float acc = fcb[tid];
    for(int c=0;c<128;c++) acc += mean[c]*fcW[c*NC_ + tid];
    out[b*NC_ + tid] = acc;
  }
}

// ---------------- launch ----------------
extern "C" void kernel_launch(void* const* d_in, const int* in_sizes, int n_in,
                              void* d_out, int out_size, void* d_ws, size_t ws_size,
                              hipStream_t stream)
{
  const float* X   = (const float*)d_in[0];
  const int*   ei  = (const int*)  d_in[1];
  const float* W1  = (const float*)d_in[2];
  const float* s1W = (const float*)d_in[3];
  const float* g1  = (const float*)d_in[5];
  const float* b1  = (const float*)d_in[6];
  const float* W2  = (const float*)d_in[7];
  const float* s2W = (const float*)d_in[8];
  const float* g2  = (const float*)d_in[10];
  const float* b2  = (const float*)d_in[11];
  const float* c1W = (const float*)d_in[12];
  const float* tg1 = (const float*)d_in[14];
  const float* tb1 = (const float*)d_in[15];
  const float* c2W = (const float*)d_in[16];
  const float* tg2 = (const float*)d_in[18];
  const float* tb2 = (const float*)d_in[19];
  const float* fcW = (const float*)d_in[20];
  const float* fcb = (const float*)d_in[21];

  char* ws = (char*)d_ws;
  unsigned char* H = (unsigned char*)(ws);           // H2 fp8, 52 MB
  bf16*  C1b    = (bf16*) (ws + 104857600);
  float* cpart1 = (float*)(ws + 109051904);
  float* cpart2 = (float*)(ws + 109576192);
  float* part   = (float*)(ws + 113246208);          // 16.7 MB: gram/BN2 partials; later C2 bf16
  float* gpart  = part;
  short* C2b    = (short*)part;
  float* hpart  = cpart1;
  bf16*  Wb     = (bf16*) (ws + 130023424);
  bf16*  Wb2    = (bf16*) (ws + 131252224);
  bf16*  WbB    = (bf16*) (ws + 131350528);
  float* stats  = (float*)(ws + 131366912);
  bf16*  W6f    = (bf16*) (stats);
  float* scale1 = stats + 131456; float* shift1 = scale1 + 32768;
  float* scale2 = shift1 + 32768; float* shift2 = scale2 + 32768;
  float* scale3 = shift2 + 32768; float* shift3 = scale3 + 64;
  float* scale4 = shift3 + 64;    float* shift4 = scale4 + 128;
  int* csr_off = (int*)(shift4 + 128);
  int* csr_lst = csr_off + 32;

  k_wt<<<256, 256, 0, stream>>>(c1W, c2W, s2W, W2, s1W, W1, ei, Wb, Wb2, WbB, W6f, csr_off, csr_lst);

  k_stats1<<<dim3(T_/16, B_), 512, 0, stream>>>(X, csr_off, csr_lst, gpart);
  k_bnfin1<<<128, 256, 0, stream>>>(gpart, s1W, W1, g1, b1, scale1, shift1);
  k_gcn2<<<dim3(T_/16, B_), 512, 0, stream>>>(X, scale1, shift1, W6f, WbB, csr_off, csr_lst, H, part);
  k_bnfin_th<<<128, 256, 0, stream>>>(part, g2, b2, scale2, shift2);
  k_conv1<<<dim3(16, B_), 256, 0, stream>>>(H, scale2, shift2, Wb, C1b, cpart1);
  k_redch<<<64, 256, 0, stream>>>(cpart1, tg1, tb1, scale3, shift3, 64, 1024, 1.0f/32768.0f);
  k_conv2<<<dim3(8, B_), 256, 0, stream>>>(C1b, scale3, shift3, Wb2, C2b, cpart2);
  k_redch<<<128, 256, 0, stream>>>(cpart2, tg2, tb2, scale4, shift4, 128, 512, 1.0f/32768.0f);
  k_head1<<<dim3(4, B_), 256, 0, stream>>>(C2b, scale4, shift4, hpart);
  k_head2<<<B_, 128, 0, stream>>>(hpart, fcW, fcb, (float*)d_out);
}

// Round 17
// 197.026 us; speedup vs baseline: 1.8351x; 1.0226x over previous
//
#include <hip/hip_runtime.h>
#include <hip/hip_bf16.h>
#include <cstddef>

using bf16 = __hip_bfloat16;
typedef __attribute__((ext_vector_type(4)))  short bf16x4;
typedef __attribute__((ext_vector_type(8)))  short bf16x8;
typedef __attribute__((ext_vector_type(4)))  float f32x4;
typedef __attribute__((ext_vector_type(16))) float f32x16;
typedef __attribute__((ext_vector_type(2)))  unsigned int uint32x2;
typedef __attribute__((ext_vector_type(4)))  unsigned int uint32x4;

#define B_   64
#define T_   512
#define V_   25
#define HD_  64
#define E_   48
#define NC_  60

__device__ __forceinline__ bf16  f2b(float x){ return __float2bfloat16(x); }
__device__ __forceinline__ unsigned short f2bits(float x){ return __builtin_bit_cast(unsigned short, f2b(x)); }
__device__ __forceinline__ float bits2f(unsigned short s){ return __builtin_bit_cast(float, ((unsigned)s)<<16); }
__device__ __forceinline__ float rbf(float x){ return bits2f(f2bits(x)); }
__device__ __forceinline__ unsigned cvtpk(float lo, float hi){
  unsigned r;
  asm("v_cvt_pk_bf16_f32 %0, %1, %2" : "=v"(r) : "v"(lo), "v"(hi));
  return r;
}
__device__ __forceinline__ short cvt1(float x){ return (short)(unsigned short)cvtpk(x, x); }

// ---------------- prep: weight packing + CSR ----------------
__global__ void k_wt(const float* __restrict__ c1W, const float* __restrict__ c2W,
                     const float* __restrict__ s2W, const float* __restrict__ W2,
                     const float* __restrict__ s1W, const float* __restrict__ W1,
                     const int* __restrict__ ei,
                     bf16* __restrict__ Wb, bf16* __restrict__ Wb2,
                     bf16* __restrict__ WbB, bf16* __restrict__ W6f,
                     int* __restrict__ offs, int* __restrict__ lst)
{
  int i0 = blockIdx.x*blockDim.x + threadIdx.x, stride = gridDim.x*blockDim.x;
  if(blockIdx.x == 0 && threadIdx.x == 0){
    int cnt[V_], pos[V_];
    for(int v=0;v<V_;v++) cnt[v]=0;
    for(int e=0;e<E_;e++) cnt[ei[2*e+1]]++;
    int off = 0;
    for(int v=0;v<V_;v++){ offs[v]=off; pos[v]=off; off+=cnt[v]; }
    offs[V_] = off;
    for(int e=0;e<E_;e++){ int d = ei[2*e+1]; lst[pos[d]++] = ei[2*e+0]; }
  }
  for(int i = i0; i < 307200; i += stride){
    int hlo = i & 15, o = (i>>4)&63, kc = (i>>10)%12, v = i/12288;
    int ks = kc>>2, h = (kc&3)*16 + hlo;
    Wb[i] = f2b(c1W[(o*1600 + v*64 + h)*3 + ks]);
  }
  for(int i = i0; i < 24576; i += stride){
    int hlo = i & 15, o = (i>>4)&127, kc = i>>11;
    int ks = kc>>2, c = (kc&3)*16 + hlo;
    Wb2[i] = f2b(c2W[(o*64 + c)*3 + ks]);
  }
  for(int i = i0; i < 8192; i += stride){
    int j = i&7, l=(i>>3)&63, n=(i>>9)&3, kt=i>>11;
    int k = kt*32 + (l>>4)*8 + j;
    int h = n*16 + (l&15);
    float val = (k < 64) ? s2W[k*64 + h] : W2[(k-64)*64 + h];
    WbB[i] = f2b(val);
  }
  for(int i = i0; i < 2048; i += stride){
    int j = i&7, l=(i>>3)&63, n=(i>>9)&3;
    int k = (l>>4)*8 + j, h = n*16 + (l&15);
    float val = 0.f;
    if(k < 3) val = s1W[k*64 + h];
    else if(k < 6) val = W1[(k-3)*64 + h];
    W6f[i] = f2b(val);
  }
}

// ---------------- BN1 stats via 6x6 Gram partials ----------------
__global__ __launch_bounds__(512) void k_stats1(
    const float* __restrict__ X,
    const int* __restrict__ offs, const int* __restrict__ lst,
    float* __restrict__ gpart)
{
  int tid = threadIdx.x;
  int b = blockIdx.y, t0 = blockIdx.x*16;
  __shared__ short Xs[1248];
  __shared__ short Z6[3200];
  __shared__ unsigned char soc[32], slc[48];

  if(tid < V_+1) soc[tid] = (unsigned char)offs[tid];
  else if(tid >= 64 && tid < 64+E_) slc[tid-64] = (unsigned char)lst[tid-64];
  for(int i=tid; i<1248; i+=512){
    int c = i/416, r = i - c*416, tl = r/26, v = r - tl*26;
    short val = 0;
    if(v < 25) val = cvt1(X[((size_t)(b*3+c)*T_ + t0+tl)*V_ + v]);
    Xs[i] = val;
  }
  __syncthreads();
  if(tid < 400){
    int v = tid>>4, tl = tid&15, xb = tl*26;
    float a0=0.f, a1=0.f, a2=0.f;
    int e1 = soc[v+1];
    for(int e=soc[v]; e<e1; e++){
      int u = slc[e];
      a0 += bits2f((unsigned short)Xs[xb+u]);
      a1 += bits2f((unsigned short)Xs[416+xb+u]);
      a2 += bits2f((unsigned short)Xs[832+xb+u]);
    }
    unsigned p01 = cvtpk(a0, a1);
    bf16x8 z;
    z[0]=Xs[xb+v]; z[1]=Xs[416+xb+v]; z[2]=Xs[832+xb+v];
    z[3]=(short)p01; z[4]=(short)(p01>>16); z[5]=cvt1(a2);
    z[6]=0; z[7]=0;
    *(bf16x8*)&Z6[tid*8] = z;
  }
  __syncthreads();

  int t = tid>>5, item = tid&31;
  if(item < 27){
    int k = item, kk = -1;
    if(item >= 6){
      int r = item - 6; k = 0;
      while(r >= 6-k){ r -= 6-k; k++; }
      kk = k + r;
    }
    float acc = 0.f;
    for(int v=0;v<25;v++){
      const short* z = &Z6[(v*16 + t)*8];
      float a = bits2f((unsigned short)z[k]);
      if(kk < 0) acc += a;
      else acc += a * bits2f((unsigned short)z[kk]);
    }
    gpart[((size_t)blockIdx.x*64 + b)*432 + t*27 + item] = acc;
  }
}

// ---------------- BN1 finalize from Gram partials ----------------
__global__ __launch_bounds__(256) void k_bnfin1(
    const float* __restrict__ gpart,
    const float* __restrict__ s1W, const float* __restrict__ W1,
    const float* __restrict__ g, const float* __restrict__ bt,
    float* __restrict__ scale, float* __restrict__ shift)
{
  int tid = threadIdx.x;
  int t0 = blockIdx.x*4;
  int tx = t0 >> 4, tlb = t0 & 15;
  __shared__ float SM[4][27];
  __shared__ float Wsh[6][64];
  for(int i=tid; i<108; i+=256){
    int tl = i/27, item = i%27;
    float s = 0.f;
    for(int b=0;b<64;b++)
      s += gpart[((size_t)tx*64 + b)*432 + (tlb+tl)*27 + item];
    SM[tl][item] = s;
  }
  for(int i=tid; i<384; i+=256){
    int k = i>>6, h = i&63;
    float w = (k<3) ? s1W[k*64+h] : W1[(k-3)*64+h];
    Wsh[k][h] = rbf(w);
  }
  __syncthreads();
  int tl = tid>>6, h = tid&63;
  float w[6];
  #pragma unroll
  for(int k=0;k<6;k++) w[k] = Wsh[k][h];
  float lin = 0.f;
  #pragma unroll
  for(int k=0;k<6;k++) lin += w[k]*SM[tl][k];
  float qq = 0.f;
  int idx = 6;
  #pragma unroll
  for(int k=0;k<6;k++){
    #pragma unroll 6
    for(int kk=k;kk<6;kk++){
      float c = w[k]*w[kk];
      if(kk != k) c += c;
      qq += c*SM[tl][idx++];
    }
  }
  float m = lin * (1.0f/1600.0f);
  float v = qq * (1.0f/1600.0f) - m*m;
  float r = rsqrtf(fmaxf(v, 0.f) + 1e-5f);
  float sc = g[h]*r;
  scale[(t0+tl)*64 + h] = sc;
  shift[(t0+tl)*64 + h] = bt[h] - m*sc;
}

// ---------------- per-(t,h) BN finalize from block partials (BN2) ----------------
__global__ void k_bnfin_th(const float* __restrict__ part,
                           const float* __restrict__ g, const float* __restrict__ bt,
                           float* __restrict__ scale, float* __restrict__ shift)
{
  int i = blockIdx.x*blockDim.x + threadIdx.x;
  if(i < T_*HD_){
    int h = i & 63, t = i >> 6, bx = t >> 4, tl = t & 15;
    const float* p = part + ((size_t)bx*64)*2048 + tl*64 + h;
    float s = 0.f, q = 0.f;
    for(int b=0;b<64;b++){ s += p[(size_t)b*2048]; q += p[(size_t)b*2048 + 1024]; }
    float m = s * (1.0f/1600.0f);
    float v = q * (1.0f/1600.0f) - m*m;
    float r = rsqrtf(fmaxf(v, 0.f) + 1e-5f);
    float sc = g[h]*r;
    scale[i] = sc;
    shift[i] = bt[h] - m*sc;
  }
}

// ---------------- GCN layer 2: MFMA recompute of H1 + MFMA layer-2, write H2 (fp8, [b][v][t][h]) ----------------
__global__ __launch_bounds__(512,4) void k_gcn2(
    const float* __restrict__ X,
    const float* __restrict__ scale1, const float* __restrict__ shift1,
    const bf16* __restrict__ W6f, const bf16* __restrict__ WbB,
    const int* __restrict__ offs, const int* __restrict__ lst,
    unsigned char* __restrict__ Hout, float* __restrict__ part)
{
  int tid = threadIdx.x, lane = tid & 63, wid = tid >> 6;
  int b = blockIdx.y, t0 = blockIdx.x*16;
  __shared__ short Zs[400*72];
  __shared__ short WbBs[8192];
  __shared__ unsigned int pss[1024];
  __shared__ unsigned char soc[32], slc[48];
  short* Z6 = Zs;
  short* Xs = Zs + 3200;

  bf16x8 w6[4];
  #pragma unroll
  for(int n=0;n<4;n++) w6[n] = *(const bf16x8*)&W6f[(n*64 + lane)*8];

  if(tid < V_+1) soc[tid] = (unsigned char)offs[tid];
  else if(tid >= 64 && tid < 64+E_) slc[tid-64] = (unsigned char)lst[tid-64];
  for(int i=tid; i<1024; i+=512){
    pss[i] = ((unsigned)f2bits(shift1[t0*64+i])<<16) | f2bits(scale1[t0*64+i]);
    *(bf16x8*)&WbBs[i*8] = *(const bf16x8*)&WbB[i*8];
  }
  for(int i=tid; i<1248; i+=512){
    int c = i/416, r = i - c*416, tl = r/26, v = r - tl*26;
    short val = 0;
    if(v < 25) val = cvt1(X[((size_t)(b*3+c)*T_ + t0+tl)*V_ + v]);
    Xs[i] = val;
  }
  __syncthreads();

  if(tid < 400){
    int v = tid>>4, tl = tid&15, xb = tl*26;
    float a0=0.f, a1=0.f, a2=0.f;
    int e1 = soc[v+1];
    for(int e=soc[v]; e<e1; e++){
      int u = slc[e];
      a0 += bits2f((unsigned short)Xs[xb+u]);
      a1 += bits2f((unsigned short)Xs[416+xb+u]);
      a2 += bits2f((unsigned short)Xs[832+xb+u]);
    }
    unsigned p01 = cvtpk(a0, a1);
    bf16x8 z;
    z[0]=Xs[xb+v]; z[1]=Xs[416+xb+v]; z[2]=Xs[832+xb+v];
    z[3]=(short)p01; z[4]=(short)(p01>>16); z[5]=cvt1(a2);
    z[6]=0; z[7]=0;
    *(bf16x8*)&Z6[tid*8] = z;
  }
  __syncthreads();

  // pass 1: H1pre = Z6 @ W6
  f32x4 c1f[4][4] = {};
  #pragma unroll
  for(int vi=0; vi<4; vi++){
    int v = wid + vi*8;
    if(v < V_){
      bf16x8 af = {0,0,0,0,0,0,0,0};
      if(lane < 16) af = *(const bf16x8*)&Z6[(v*16 + lane)*8];
      #pragma unroll
      for(int n=0;n<4;n++)
        c1f[vi][n] = __builtin_amdgcn_mfma_f32_16x16x32_bf16(af, w6[n], c1f[vi][n], 0, 0, 0);
    }
  }
  __syncthreads();

  // epilogue 1: bn1 + relu + pack into Zs
  int l15 = lane & 15, tlb = (lane>>4)*4;
  #pragma unroll
  for(int vi=0; vi<4; vi++){
    int v = wid + vi*8;
    if(v < V_){
      #pragma unroll
      for(int n=0;n<4;n++){
        float y[4];
        #pragma unroll
        for(int j=0;j<4;j++){
          unsigned u = pss[(tlb+j)*64 + n*16 + l15];
          y[j] = fmaxf(c1f[vi][n][j]*bits2f((unsigned short)(u&0xffffu)) + bits2f((unsigned short)(u>>16)), 0.f);
        }
        unsigned p01 = cvtpk(y[0], y[1]), p23 = cvtpk(y[2], y[3]);
        short* base = &Zs[(v*16 + tlb)*72 + n*16 + l15];
        base[0]   = (short)p01;  base[72]  = (short)(p01>>16);
        base[144] = (short)p23;  base[216] = (short)(p23>>16);
      }
    }
  }
  __syncthreads();

  // pass 2: layer-2 MFMA with in-register neighbor aggregation
  int cg = (lane>>4)*8;
  f32x4 accs[4][4] = {};
  #pragma unroll
  for(int vi=0; vi<4; vi++){
    int v = wid + vi*8;
    if(v < V_){
      const short* rowp = &Zs[(v*16 + l15)*72 + cg];
      bf16x8 a0 = *(const bf16x8*)rowp;
      bf16x8 a1 = *(const bf16x8*)(rowp + 32);
      float s0[8]={0,0,0,0,0,0,0,0}, s1[8]={0,0,0,0,0,0,0,0};
      int e1 = soc[v+1];
      for(int e=soc[v]; e<e1; e++){
        int u = slc[e];
        const short* np = &Zs[(u*16 + l15)*72 + cg];
        bf16x8 n0 = *(const bf16x8*)np;
        bf16x8 n1 = *(const bf16x8*)(np + 32);
        #pragma unroll
        for(int j=0;j<8;j++){ s0[j] += bits2f((unsigned short)n0[j]); s1[j] += bits2f((unsigned short)n1[j]); }
      }
      uint32x4 ua2, ua3;
      #pragma unroll
      for(int j=0;j<4;j++){ ua2[j] = cvtpk(s0[2*j], s0[2*j+1]); ua3[j] = cvtpk(s1[2*j], s1[2*j+1]); }
      bf16x8 a2 = __builtin_bit_cast(bf16x8, ua2);
      bf16x8 a3 = __builtin_bit_cast(bf16x8, ua3);
      #pragma unroll
      for(int n=0;n<4;n++){
        bf16x8 b0 = *(const bf16x8*)&WbBs[(( 0+n)*64 + lane)*8];
        accs[vi][n] = __builtin_amdgcn_mfma_f32_16x16x32_bf16(a0, b0, accs[vi][n], 0, 0, 0);
        bf16x8 b1 = *(const bf16x8*)&WbBs[(( 4+n)*64 + lane)*8];
        accs[vi][n] = __builtin_amdgcn_mfma_f32_16x16x32_bf16(a1, b1, accs[vi][n], 0, 0, 0);
        bf16x8 b2 = *(const bf16x8*)&WbBs[(( 8+n)*64 + lane)*8];
        accs[vi][n] = __builtin_amdgcn_mfma_f32_16x16x32_bf16(a2, b2, accs[vi][n], 0, 0, 0);
        bf16x8 b3 = *(const bf16x8*)&WbBs[((12+n)*64 + lane)*8];
        accs[vi][n] = __builtin_amdgcn_mfma_f32_16x16x32_bf16(a3, b3, accs[vi][n], 0, 0, 0);
      }
    }
  }
  __syncthreads();

  // epilogue 2: stats + bf16 write-back IN PLACE (same rows as epi1; no transpose)
  f32x4 ssum[4] = {}, ssq[4] = {};
  #pragma unroll
  for(int vi=0; vi<4; vi++){
    int v = wid + vi*8;
    if(v < V_){
      #pragma unroll
      for(int n=0;n<4;n++){
        float val[4];
        #pragma unroll
        for(int j=0;j<4;j++){
          val[j] = accs[vi][n][j];
          ssum[n][j] += val[j]; ssq[n][j] += val[j]*val[j];
        }
        unsigned p01 = cvtpk(val[0], val[1]), p23 = cvtpk(val[2], val[3]);
        short* base = &Zs[(v*16 + tlb)*72 + n*16 + l15];
        base[0]   = (short)p01;  base[72]  = (short)(p01>>16);
        base[144] = (short)p23;  base[216] = (short)(p23>>16);
      }
    }
  }
  __syncthreads();

  // coop store: rows v*16+tl -> H2[b][v][t0+tl][h] fp8 (25 contiguous 1KB chunks)
  for(int c=tid; c<3200; c+=512){
    int rr = c>>3, h8 = c&7, v = rr>>4, tl = rr&15;
    bf16x8 o = *(const bf16x8*)&Zs[rr*72 + h8*8];
    float f[8];
    #pragma unroll
    for(int j=0;j<8;j++) f[j] = bits2f((unsigned short)o[j]);
    int w0 = 0, w1 = 0;
    w0 = __builtin_amdgcn_cvt_pk_fp8_f32(f[0], f[1], w0, false);
    w0 = __builtin_amdgcn_cvt_pk_fp8_f32(f[2], f[3], w0, true);
    w1 = __builtin_amdgcn_cvt_pk_fp8_f32(f[4], f[5], w1, false);
    w1 = __builtin_amdgcn_cvt_pk_fp8_f32(f[6], f[7], w1, true);
    uint32x2 st; st.x = (unsigned)w0; st.y = (unsigned)w1;
    __builtin_nontemporal_store(st, (uint32x2*)&Hout[(((size_t)b*V_ + v)*T_ + t0 + tl)*64 + h8*8]);
  }
  __syncthreads();

  // stats: two conflict-free passes through red = Zs
  float* red = (float*)Zs;
  size_t pb = ((size_t)blockIdx.x*64 + blockIdx.y)*2048;
  #pragma unroll
  for(int n=0;n<4;n++)
    #pragma unroll
    for(int j=0;j<4;j++)
      red[wid*1024 + (tlb+j)*64 + n*16 + l15] = ssum[n][j];
  __syncthreads();
  for(int i=tid; i<1024; i+=512){
    float s = 0.f;
    #pragma unroll
    for(int w=0;w<8;w++) s += red[w*1024 + i];
    __builtin_nontemporal_store(s, &part[pb + i]);
  }
  __syncthreads();
  #pragma unroll
  for(int n=0;n<4;n++)
    #pragma unroll
    for(int j=0;j<4;j++)
      red[wid*1024 + (tlb+j)*64 + n*16 + l15] = ssq[n][j];
  __syncthreads();
  for(int i=tid; i<1024; i+=512){
    float q = 0.f;
    #pragma unroll
    for(int w=0;w<8;w++) q += red[w*1024 + i];
    __builtin_nontemporal_store(q, &part[pb + 1024 + i]);
  }
}

// ---------------- conv1: 32-t tiles, in-block v-split, depth-2 prefetch (H2 in [b][v][t][h]) ----------------
__device__ __forceinline__ uint32x2 loadH8(const unsigned char* H, int b, int v, int t0, int s){
  int ti = s>>3, h0 = (s&7)*8, t = t0-1+ti;
  uint32x2 r; r.x = 0u; r.y = 0u;
  if(t >= 0 && t < T_) r = *(const uint32x2*)&H[(((size_t)b*V_ + v)*T_ + t)*HD_ + h0];
  return r;
}

__device__ __forceinline__ void xform_store(short* zbuf, const unsigned int* sshf, int s, uint32x2 raw){
  int ti = s>>3, h0 = (s&7)*8;
  uint4 u0 = *(const uint4*)&sshf[ti*64 + h0];
  uint4 u1 = *(const uint4*)&sshf[ti*64 + h0 + 4];
  unsigned int uu[8] = {u0.x,u0.y,u0.z,u0.w,u1.x,u1.y,u1.z,u1.w};
  float x[8];
  x[0] = __builtin_amdgcn_cvt_f32_fp8((int)raw.x, 0);
  x[1] = __builtin_amdgcn_cvt_f32_fp8((int)raw.x, 1);
  x[2] = __builtin_amdgcn_cvt_f32_fp8((int)raw.x, 2);
  x[3] = __builtin_amdgcn_cvt_f32_fp8((int)raw.x, 3);
  x[4] = __builtin_amdgcn_cvt_f32_fp8((int)raw.y, 0);
  x[5] = __builtin_amdgcn_cvt_f32_fp8((int)raw.y, 1);
  x[6] = __builtin_amdgcn_cvt_f32_fp8((int)raw.y, 2);
  x[7] = __builtin_amdgcn_cvt_f32_fp8((int)raw.y, 3);
  float r[8];
  #pragma unroll
  for(int j=0;j<8;j++){
    float scl = bits2f((unsigned short)(uu[j] & 0xffffu));
    float shf = bits2f((unsigned short)(uu[j] >> 16));
    r[j] = fmaxf(x[j]*scl + shf, 0.f);
  }
  uint32x4 u;
  #pragma unroll
  for(int j=0;j<4;j++) u[j] = cvtpk(r[2*j], r[2*j+1]);
  *(uint32x4*)&zbuf[ti*72 + h0] = u;
}

__global__ __launch_bounds__(256) void k_conv1(
    const unsigned char* __restrict__ H, const float* __restrict__ scale2, const float* __restrict__ shift2,
    const bf16* __restrict__ Wb, bf16* __restrict__ C1b, float* __restrict__ cpart1)
{
  int b = blockIdx.y, t0 = blockIdx.x*32, tid = threadIdx.x;
  int lane = tid & 63, w = tid >> 6;
  __shared__ unsigned int sshf[34*64];
  __shared__ short zs[2][2][34*72];

  for(int i = tid; i < 34*64; i += 256){
    int ti = i>>6, h = i&63, t = t0-1+ti;
    unsigned int u = 0;
    if(t >= 0 && t < T_){
      u = ((unsigned)f2bits(shift2[t*64+h])<<16) | f2bits(scale2[t*64+h]);
    }
    sshf[i] = u;
  }
  __syncthreads();

  {
    uint32x2 a0 = loadH8(H,b,0,t0,tid);
    uint32x2 b0 = loadH8(H,b,13,t0,tid);
    uint32x2 a1, b1; a1.x=a1.y=b1.x=b1.y=0u;
    if(tid<16){ a1 = loadH8(H,b,0,t0,tid+256); b1 = loadH8(H,b,13,t0,tid+256); }
    xform_store(&zs[0][0][0], sshf, tid, a0);
    xform_store(&zs[1][0][0], sshf, tid, b0);
    if(tid<16){ xform_store(&zs[0][0][0], sshf, tid+256, a1); xform_store(&zs[1][0][0], sshf, tid+256, b1); }
  }
  uint32x2 rA0 = loadH8(H,b,1,t0,tid), rB0 = loadH8(H,b,14,t0,tid);
  uint32x2 rA1, rB1; rA1.x=rA1.y=rB1.x=rB1.y=0u;
  if(tid<16){ rA1 = loadH8(H,b,1,t0,tid+256); rB1 = loadH8(H,b,14,t0,tid+256); }
  __syncthreads();

  int g = w >> 1;
  int o0 = (w & 1)*32;
  int vbase = g ? 13 : 0, nv = g ? 12 : 13;
  f32x16 acc = {};
  for(int i=0; i<13; i++){
    uint32x2 nA0, nA1, nB0, nB1;
    nA0.x=nA0.y=nA1.x=nA1.y=nB0.x=nB0.y=nB1.x=nB1.y=0u;
    if(i+2 < 13){
      nA0 = loadH8(H,b,i+2,t0,tid);
      if(tid<16) nA1 = loadH8(H,b,i+2,t0,tid+256);
    }
    if(i+2 < 12){
      nB0 = loadH8(H,b,13+i+2,t0,tid);
      if(tid<16) nB1 = loadH8(H,b,13+i+2,t0,tid+256);
    }
    if(i < nv){
      int v = vbase + i;
      const short* zbuf = &zs[g][i&1][0];
      #pragma unroll
      for(int kc=0; kc<12; kc++){
        int ks = kc>>2;
        bf16x8 af = *(const bf16x8*)&Wb[((v*12+kc)*64 + o0 + (lane&31))*16 + (lane>>5)*8];
        int row = (lane&31) + ks;
        int col = (kc&3)*16 + (lane>>5)*8;
        bf16x8 bfr = *(const bf16x8*)&zbuf[row*72 + col];
        acc = __builtin_amdgcn_mfma_f32_32x32x16_bf16(af, bfr, acc, 0, 0, 0);
      }
    }
    if(i+1 < 13){
      xform_store(&zs[0][(i+1)&1][0], sshf, tid, rA0);
      if(tid<16) xform_store(&zs[0][(i+1)&1][0], sshf, tid+256, rA1);
    }
    if(i+1 < 12){
      xform_store(&zs[1][(i+1)&1][0], sshf, tid, rB0);
      if(tid<16) xform_store(&zs[1][(i+1)&1][0], sshf, tid+256, rB1);
    }
    rA0=nA0; rA1=nA1; rB0=nB0; rB1=nB1;
    __syncthreads();
  }

  float* redB = (float*)&zs[0][0][0];
  short* Cs   = &zs[0][0][0] + 4224;
  if(g == 1){
    #pragma unroll
    for(int r=0;r<16;r++){
      int ol = (r&3) + 8*(r>>2) + 4*(lane>>5);
      redB[(w&1)*1056 + ol*33 + (lane&31)] = acc[r];
    }
  }
  __syncthreads();
  if(g == 0){
    #pragma unroll
    for(int r=0;r<16;r++){
      int ol = (r&3) + 8*(r>>2) + 4*(lane>>5);
      float val = acc[r] + redB[(w&1)*1056 + ol*33 + (lane&31)];
      Cs[((w&1)*32 + ol)*32 + (lane&31)] = cvt1(val);
    }
  }
  __syncthreads();

  {
    int o = tid>>2, tseg = (tid&3)*8;
    bf16x8 row = *(const bf16x8*)&Cs[o*32 + tseg];
    *(bf16x8*)&C1b[((size_t)b*64 + o)*T_ + t0 + tseg] = row;
  }
  if(tid < 64){
    float s = 0.f, q = 0.f;
    for(int t=0;t<32;t++){
      float v = bits2f((unsigned short)Cs[tid*32 + t]);
      s += v; q += v*v;
    }
    size_t pb = ((size_t)blockIdx.y*16 + blockIdx.x)*128;
    cpart1[pb + tid] = s;
    cpart1[pb + 64 + tid] = q;
  }
}

// ---------------- parallel per-channel BN finalize ----------------
__global__ __launch_bounds__(256) void k_redch(const float* __restrict__ cpart,
    const float* __restrict__ g, const float* __restrict__ bt,
    float* __restrict__ scale, float* __restrict__ shift, int nch, int nblk, float inv_count)
{
  int o = blockIdx.x, tid = threadIdx.x;
  float s = 0.f, q = 0.f;
  for(int blk=tid; blk<nblk; blk+=256){
    s += cpart[(size_t)blk*2*nch + o];
    q += cpart[(size_t)blk*2*nch + nch + o];
  }
  for(int off=32; off; off>>=1){ s += __shfl_down(s, off); q += __shfl_down(q, off); }
  __shared__ float rs[4], rq[4];
  if((tid&63)==0){ rs[tid>>6]=s; rq[tid>>6]=q; }
  __syncthreads();
  if(tid==0){
    s = rs[0]+rs[1]+rs[2]+rs[3]; q = rq[0]+rq[1]+rq[2]+rq[3];
    float m = s*inv_count;
    float v = q*inv_count - m*m;
    float r = rsqrtf(fmaxf(v, 0.f) + 1e-5f);
    float sc = g[o]*r;
    scale[o] = sc; shift[o] = bt[o] - m*sc;
  }
}

// ---------------- conv2 via MFMA + fused BN4 partials (C2 bf16) ----------------
__global__ __launch_bounds__(256) void k_conv2(
    const bf16* __restrict__ C1b, const float* __restrict__ scale3, const float* __restrict__ shift3,
    const bf16* __restrict__ Wb2, short* __restrict__ C2b, float* __restrict__ cpart)
{
  int b = blockIdx.y, t0 = blockIdx.x*64, tid = threadIdx.x;
  int lane = tid & 63, w = tid >> 6;
  __shared__ short zT[68*72];
  __shared__ float scl[64], shf[64];
  __shared__ float rpart[4][16][2][2];
  if(tid < 64){ scl[tid]=scale3[tid]; shf[tid]=shift3[tid]; }
  __syncthreads();
  for(int i=tid; i<4352; i+=256){
    int c = i/68, r = i%68, t = t0 - 2 + r;
    float val = 0.f;
    if(t >= 0 && t < T_) val = fmaxf(bits2f((unsigned short)__builtin_bit_cast(short, C1b[((size_t)b*64+c)*T_ + t]))*scl[c] + shf[c], 0.f);
    zT[r*72 + c] = cvt1(val);
  }
  __syncthreads();
  int o0 = w*32;
  float sr[16], qr[16];
  #pragma unroll
  for(int r=0;r<16;r++){ sr[r]=0.f; qr[r]=0.f; }
  #pragma unroll
  for(int tt=0; tt<2; tt++){
    int twv = tt*32;
    f32x16 acc = {};
    #pragma unroll
    for(int kc=0; kc<12; kc++){
      bf16x8 af = *(const bf16x8*)&Wb2[((kc*128) + o0 + (lane&31))*16 + (lane>>5)*8];
      bf16x8 bfr = *(const bf16x8*)&zT[(twv + (lane&31) + 2*(kc>>2))*72 + (kc&3)*16 + (lane>>5)*8];
      acc = __builtin_amdgcn_mfma_f32_32x32x16_bf16(af, bfr, acc, 0, 0, 0);
    }
    int t = t0 + twv + (lane&31);
    #pragma unroll
    for(int r=0;r<16;r++){
      int o = o0 + (r&3) + 8*(r>>2) + 4*(lane>>5);
      float y = acc[r];
      C2b[((size_t)b*128 + o)*T_ + t] = cvt1(y);
      sr[r] += y; qr[r] += y*y;
    }
  }
  #pragma unroll
  for(int r=0;r<16;r++){
    float s = sr[r], q = qr[r];
    #pragma unroll
    for(int m=1;m<=16;m<<=1){ s += __shfl_xor(s, m); q += __shfl_xor(q, m); }
    if((lane&31)==0){ rpart[w][r][lane>>5][0]=s; rpart[w][r][lane>>5][1]=q; }
  }
  __syncthreads();
  if(tid < 128){
    int wv = tid>>5, r = (tid>>1)&15, hf = tid&1;
    int o = wv*32 + (r&3) + 8*(r>>2) + 4*hf;
    size_t pb = ((size_t)(blockIdx.y*8 + blockIdx.x))*256;
    cpart[pb + o]       = rpart[wv][r][hf][0];
    cpart[pb + 128 + o] = rpart[wv][r][hf][1];
  }
}

// ---------------- head part 1: BN+ReLU + partial t-sums ----------------
__global__ __launch_bounds__(256) void k_head1(
    const short* __restrict__ C2b, const float* __restrict__ scale4, const float* __restrict__ shift4,
    float* __restrict__ hpart)
{
  int b = blockIdx.y, q = blockIdx.x, tid = threadIdx.x;
  __shared__ float ms[256];
  int ch = tid >> 1, p = tid & 1;
  float scl = scale4[ch], shf = shift4[ch];
  const short* src = C2b + ((size_t)b*128 + ch)*T_ + q*128 + p*64;
  float s = 0.f;
  for(int i=0;i<8;i++){
    bf16x8 v8 = *(const bf16x8*)&src[i*8];
    #pragma unroll
    for(int j=0;j<8;j++) s += fmaxf(bits2f((unsigned short)v8[j])*scl + shf, 0.f);
  }
  ms[tid] = s;
  __syncthreads();
  if(tid < 128) hpart[((size_t)b*4 + q)*128 + tid] = ms[2*tid] + ms[2*tid+1];
}

// ---------------- head part 2: mean + FC ----------------
__global__ __launch_bounds__(128) void k_head2(
    const float* __restrict__ hpart, const float* __restrict__ fcW, const float* __restrict__ fcb,
    float* __restrict__ out)
{
  int b = blockIdx.x, tid = threadIdx.x;
  __shared__ float mean[128];
  const float* hp = hpart + (size_t)b*512;
  mean[tid] = (hp[tid] + hp[128+tid] + hp[256+tid] + hp[384+tid]) * (1.0f/512.0f);
  __syncthreads();
  if(tid < NC_){
    float acc = fcb[tid];
    for(int c=0;c<128;c++) acc += mean[c]*fcW[c*NC_ + tid];
    out[b*NC_ + tid] = acc;
  }
}

// ---------------- launch ----------------
extern "C" void kernel_launch(void* const* d_in, const int* in_sizes, int n_in,
                              void* d_out, int out_size, void* d_ws, size_t ws_size,
                              hipStream_t stream)
{
  const float* X   = (const float*)d_in[0];
  const int*   ei  = (const int*)  d_in[1];
  const float* W1  = (const float*)d_in[2];
  const float* s1W = (const float*)d_in[3];
  const float* g1  = (const float*)d_in[5];
  const float* b1  = (const float*)d_in[6];
  const float* W2  = (const float*)d_in[7];
  const float* s2W = (const float*)d_in[8];
  const float* g2  = (const float*)d_in[10];
  const float* b2  = (const float*)d_in[11];
  const float* c1W = (const float*)d_in[12];
  const float* tg1 = (const float*)d_in[14];
  const float* tb1 = (const float*)d_in[15];
  const float* c2W = (const float*)d_in[16];
  const float* tg2 = (const float*)d_in[18];
  const float* tb2 = (const float*)d_in[19];
  const float* fcW = (const float*)d_in[20];
  const float* fcb = (const float*)d_in[21];

  char* ws = (char*)d_ws;
  unsigned char* H = (unsigned char*)(ws);           // H2 fp8 [b][v][t][h], 52 MB
  bf16*  C1b    = (bf16*) (ws + 104857600);
  float* cpart1 = (float*)(ws + 109051904);
  float* cpart2 = (float*)(ws + 109576192);
  float* part   = (float*)(ws + 113246208);          // 16.7 MB: gram/BN2 partials; later C2 bf16
  float* gpart  = part;
  short* C2b    = (short*)part;
  float* hpart  = cpart1;
  bf16*  Wb     = (bf16*) (ws + 130023424);
  bf16*  Wb2    = (bf16*) (ws + 131252224);
  bf16*  WbB    = (bf16*) (ws + 131350528);
  float* stats  = (float*)(ws + 131366912);
  bf16*  W6f    = (bf16*) (stats);
  float* scale1 = stats + 131456; float* shift1 = scale1 + 32768;
  float* scale2 = shift1 + 32768; float* shift2 = scale2 + 32768;
  float* scale3 = shift2 + 32768; float* shift3 = scale3 + 64;
  float* scale4 = shift3 + 64;    float* shift4 = scale4 + 128;
  int* csr_off = (int*)(shift4 + 128);
  int* csr_lst = csr_off + 32;

  k_wt<<<256, 256, 0, stream>>>(c1W, c2W, s2W, W2, s1W, W1, ei, Wb, Wb2, WbB, W6f, csr_off, csr_lst);

  k_stats1<<<dim3(T_/16, B_), 512, 0, stream>>>(X, csr_off, csr_lst, gpart);
  k_bnfin1<<<128, 256, 0, stream>>>(gpart, s1W, W1, g1, b1, scale1, shift1);
  k_gcn2<<<dim3(T_/16, B_), 512, 0, stream>>>(X, scale1, shift1, W6f, WbB, csr_off, csr_lst, H, part);
  k_bnfin_th<<<128, 256, 0, stream>>>(part, g2, b2, scale2, shift2);
  k_conv1<<<dim3(16, B_), 256, 0, stream>>>(H, scale2, shift2, Wb, C1b, cpart1);
  k_redch<<<64, 256, 0, stream>>>(cpart1, tg1, tb1, scale3, shift3, 64, 1024, 1.0f/32768.0f);
  k_conv2<<<dim3(8, B_), 256, 0, stream>>>(C1b, scale3, shift3, Wb2, C2b, cpart2);
  k_redch<<<128, 256, 0, stream>>>(cpart2, tg2, tb2, scale4, shift4, 128, 512, 1.0f/32768.0f);
  k_head1<<<dim3(4, B_), 256, 0, stream>>>(C2b, scale4, shift4, hpart);
  k_head2<<<B_, 128, 0, stream>>>(hpart, fcW, fcb, (float*)d_out);
}